// Round 1
// baseline (5878.241 us; speedup 1.0000x reference)
//
#include <hip/hip_runtime.h>
#include <math.h>

// FieldlineGraphForecaster: 4-layer residual message-passing GNN, fp32.
// Round 0: correct fp32 baseline. Structure: 32-row tiles, 256 threads,
// thread owns 2 cols x 8 rows; activations staged in LDS (broadcast float4
// reads), weights streamed from global (L1/L2 resident).

constexpr int H = 128;
constexpr int TILE = 32;
constexpr int NTHR = 256;

__device__ __forceinline__ float gelu_exact(float x) {
    return 0.5f * x * (1.0f + erff(x * 0.70710678118654752440f));
}

// One MLP layer step: K = K4*4 inner dim. Each thread accumulates 8 rows
// (egBase..egBase+7) x 2 cols (c0, c0+64). Activations read from LDS
// (same address across wave -> broadcast, conflict-free), weights from
// global (coalesced 256B per wave per load).
template <int K4>
__device__ __forceinline__ void mlp_layer(const float* __restrict__ W,
                                          const float* lds, int ldsStride,
                                          int c0, int egBase,
                                          float a0[8], float a1[8]) {
#pragma unroll 2
    for (int k4 = 0; k4 < K4; ++k4) {
        const float w00 = W[(k4 * 4 + 0) * H + c0];
        const float w01 = W[(k4 * 4 + 1) * H + c0];
        const float w02 = W[(k4 * 4 + 2) * H + c0];
        const float w03 = W[(k4 * 4 + 3) * H + c0];
        const float w10 = W[(k4 * 4 + 0) * H + c0 + 64];
        const float w11 = W[(k4 * 4 + 1) * H + c0 + 64];
        const float w12 = W[(k4 * 4 + 2) * H + c0 + 64];
        const float w13 = W[(k4 * 4 + 3) * H + c0 + 64];
#pragma unroll
        for (int e = 0; e < 8; ++e) {
            const float4 x = *reinterpret_cast<const float4*>(
                &lds[(egBase + e) * ldsStride + k4 * 4]);
            a0[e] = fmaf(x.x, w00, a0[e]);
            a0[e] = fmaf(x.y, w01, a0[e]);
            a0[e] = fmaf(x.z, w02, a0[e]);
            a0[e] = fmaf(x.w, w03, a0[e]);
            a1[e] = fmaf(x.x, w10, a1[e]);
            a1[e] = fmaf(x.y, w11, a1[e]);
            a1[e] = fmaf(x.z, w12, a1[e]);
            a1[e] = fmaf(x.w, w13, a1[e]);
        }
    }
}

// ---------------- encoder: [N,16] -> GELU MLP -> h [N,128] ----------------
__global__ __launch_bounds__(NTHR) void encode_kernel(
    const float* __restrict__ nf, const float* __restrict__ W1,
    const float* __restrict__ b1, const float* __restrict__ W2,
    const float* __restrict__ b2, float* __restrict__ h, int N) {
    __shared__ float xin[TILE * 16];  // 2KB
    __shared__ float hm[TILE * H];    // 16KB
    const int t = threadIdx.x;
    const int n0 = blockIdx.x * TILE;
    const int c0 = t & 63;
    const int eg = t >> 6;

    for (int i = t; i < TILE * 16; i += NTHR) {
        const int gi = n0 * 16 + i;
        xin[i] = (gi < N * 16) ? nf[gi] : 0.f;
    }
    __syncthreads();

    float a0[8], a1[8];
#pragma unroll
    for (int e = 0; e < 8; ++e) { a0[e] = 0.f; a1[e] = 0.f; }
    mlp_layer<4>(W1, xin, 16, c0, eg * 8, a0, a1);
    {
        const float bb0 = b1[c0], bb1 = b1[c0 + 64];
#pragma unroll
        for (int e = 0; e < 8; ++e) {
            hm[(eg * 8 + e) * H + c0] = gelu_exact(a0[e] + bb0);
            hm[(eg * 8 + e) * H + c0 + 64] = gelu_exact(a1[e] + bb1);
        }
    }
    __syncthreads();
#pragma unroll
    for (int e = 0; e < 8; ++e) { a0[e] = 0.f; a1[e] = 0.f; }
    mlp_layer<32>(W2, hm, H, c0, eg * 8, a0, a1);
    const float bb0 = b2[c0], bb1 = b2[c0 + 64];
#pragma unroll
    for (int e = 0; e < 8; ++e) {
        const int n = n0 + eg * 8 + e;
        if (n < N) {
            h[n * H + c0] = a0[e] + bb0;
            h[n * H + c0 + 64] = a1[e] + bb1;
        }
    }
}

// ---- edge message: concat(h[src],h[dst]) -> MLP -> atomicAdd agg[dst] ----
__global__ __launch_bounds__(NTHR) void edge_kernel(
    const float* __restrict__ h, const int* __restrict__ src,
    const int* __restrict__ dst, const float* __restrict__ W1,
    const float* __restrict__ b1, const float* __restrict__ W2,
    const float* __restrict__ b2, float* __restrict__ agg, int E) {
    __shared__ float xin[TILE * 256];  // 32KB, reused as hm [TILE][128]
    __shared__ int sIdx[TILE];
    __shared__ int dIdx[TILE];
    const int t = threadIdx.x;
    const int e0 = blockIdx.x * TILE;
    const int c0 = t & 63;
    const int eg = t >> 6;

    if (t < TILE)
        sIdx[t] = (e0 + t < E) ? src[e0 + t] : 0;
    else if (t < 2 * TILE)
        dIdx[t - TILE] = (e0 + t - TILE < E) ? dst[e0 + t - TILE] : 0;
    __syncthreads();

    {
        const int col = t & 127;
        const int half = t >> 7;
        for (int e = 0; e < TILE; ++e) {
            const int n = half ? dIdx[e] : sIdx[e];
            xin[e * 256 + half * H + col] = h[n * H + col];
        }
    }
    __syncthreads();

    float a0[8], a1[8];
#pragma unroll
    for (int e = 0; e < 8; ++e) { a0[e] = 0.f; a1[e] = 0.f; }
    mlp_layer<64>(W1, xin, 256, c0, eg * 8, a0, a1);
    __syncthreads();  // everyone done reading xin
    float* hm = xin;  // reuse as [TILE][128]
    {
        const float bb0 = b1[c0], bb1 = b1[c0 + 64];
#pragma unroll
        for (int e = 0; e < 8; ++e) {
            hm[(eg * 8 + e) * H + c0] = gelu_exact(a0[e] + bb0);
            hm[(eg * 8 + e) * H + c0 + 64] = gelu_exact(a1[e] + bb1);
        }
    }
    __syncthreads();
#pragma unroll
    for (int e = 0; e < 8; ++e) { a0[e] = 0.f; a1[e] = 0.f; }
    mlp_layer<32>(W2, hm, H, c0, eg * 8, a0, a1);
    const float bb0 = b2[c0], bb1 = b2[c0 + 64];
#pragma unroll
    for (int e = 0; e < 8; ++e) {
        if (e0 + eg * 8 + e < E) {
            const int d = dIdx[eg * 8 + e];
            atomicAdd(&agg[d * H + c0], a0[e] + bb0);
            atomicAdd(&agg[d * H + c0 + 64], a1[e] + bb1);
        }
    }
}

// ------- node update: h += MLP(concat(h, agg)) (residual, in-place) -------
__global__ __launch_bounds__(NTHR) void node_kernel(
    float* __restrict__ h, const float* __restrict__ agg,
    const float* __restrict__ W1, const float* __restrict__ b1,
    const float* __restrict__ W2, const float* __restrict__ b2, int N) {
    __shared__ float xin[TILE * 256];
    const int t = threadIdx.x;
    const int n0 = blockIdx.x * TILE;
    const int c0 = t & 63;
    const int eg = t >> 6;
    {
        const int col = t & 127;
        const int half = t >> 7;
        const float* srcp = half ? agg : h;
        for (int e = 0; e < TILE; ++e) {
            const int n = n0 + e;
            xin[e * 256 + half * H + col] = (n < N) ? srcp[n * H + col] : 0.f;
        }
    }
    __syncthreads();

    float a0[8], a1[8];
#pragma unroll
    for (int e = 0; e < 8; ++e) { a0[e] = 0.f; a1[e] = 0.f; }
    mlp_layer<64>(W1, xin, 256, c0, eg * 8, a0, a1);
    __syncthreads();
    float* hm = xin;
    {
        const float bb0 = b1[c0], bb1 = b1[c0 + 64];
#pragma unroll
        for (int e = 0; e < 8; ++e) {
            hm[(eg * 8 + e) * H + c0] = gelu_exact(a0[e] + bb0);
            hm[(eg * 8 + e) * H + c0 + 64] = gelu_exact(a1[e] + bb1);
        }
    }
    __syncthreads();
#pragma unroll
    for (int e = 0; e < 8; ++e) { a0[e] = 0.f; a1[e] = 0.f; }
    mlp_layer<32>(W2, hm, H, c0, eg * 8, a0, a1);
    const float bb0 = b2[c0], bb1 = b2[c0 + 64];
#pragma unroll
    for (int e = 0; e < 8; ++e) {
        const int n = n0 + eg * 8 + e;
        if (n < N) {
            h[n * H + c0] += a0[e] + bb0;
            h[n * H + c0 + 64] += a1[e] + bb1;
        }
    }
}

// --------------- decoder: h -> GELU MLP -> out [N,8] ----------------------
__global__ __launch_bounds__(NTHR) void decode_kernel(
    const float* __restrict__ h, const float* __restrict__ W1,
    const float* __restrict__ b1, const float* __restrict__ W2,
    const float* __restrict__ b2, float* __restrict__ out, int N) {
    __shared__ float xin[TILE * H];    // 16KB
    __shared__ float hm[TILE * 132];   // padded stride: kills bank conflicts
    const int t = threadIdx.x;
    const int n0 = blockIdx.x * TILE;
    const int c0 = t & 63;
    const int eg = t >> 6;
    {
        const int col = t & 127;
        for (int e = t >> 7; e < TILE; e += 2) {
            const int n = n0 + e;
            xin[e * H + col] = (n < N) ? h[n * H + col] : 0.f;
        }
    }
    __syncthreads();

    float a0[8], a1[8];
#pragma unroll
    for (int e = 0; e < 8; ++e) { a0[e] = 0.f; a1[e] = 0.f; }
    mlp_layer<32>(W1, xin, H, c0, eg * 8, a0, a1);
    {
        const float bb0 = b1[c0], bb1 = b1[c0 + 64];
#pragma unroll
        for (int e = 0; e < 8; ++e) {
            hm[(eg * 8 + e) * 132 + c0] = gelu_exact(a0[e] + bb0);
            hm[(eg * 8 + e) * 132 + c0 + 64] = gelu_exact(a1[e] + bb1);
        }
    }
    __syncthreads();
    {
        const int e = t >> 3;  // 0..31
        const int o = t & 7;
        const int n = n0 + e;
        float acc = b2[o];
#pragma unroll 4
        for (int k = 0; k < H; ++k)
            acc = fmaf(hm[e * 132 + k], W2[k * 8 + o], acc);
        if (n < N) out[n * 8 + o] = acc;
    }
}

extern "C" void kernel_launch(void* const* d_in, const int* in_sizes, int n_in,
                              void* d_out, int out_size, void* d_ws,
                              size_t ws_size, hipStream_t stream) {
    (void)n_in; (void)out_size; (void)ws_size;
    const float* nf      = (const float*)d_in[0];
    const int*   ei      = (const int*)d_in[1];
    const float* enc_W1  = (const float*)d_in[2];
    const float* enc_b1  = (const float*)d_in[3];
    const float* enc_W2  = (const float*)d_in[4];
    const float* enc_b2  = (const float*)d_in[5];
    const float* edge_W1 = (const float*)d_in[6];
    const float* edge_b1 = (const float*)d_in[7];
    const float* edge_W2 = (const float*)d_in[8];
    const float* edge_b2 = (const float*)d_in[9];
    const float* node_W1 = (const float*)d_in[10];
    const float* node_b1 = (const float*)d_in[11];
    const float* node_W2 = (const float*)d_in[12];
    const float* node_b2 = (const float*)d_in[13];
    const float* dec_W1  = (const float*)d_in[14];
    const float* dec_b1  = (const float*)d_in[15];
    const float* dec_W2  = (const float*)d_in[16];
    const float* dec_b2  = (const float*)d_in[17];

    const int N = in_sizes[0] / 16;
    const int E = in_sizes[1] / 2;
    const int L = in_sizes[7] / H;  // edge_b1 is [L,H]

    float* h   = (float*)d_ws;                 // [N,H]
    float* agg = h + (size_t)N * H;            // [N,H]

    const int nodeBlocks = (N + TILE - 1) / TILE;
    const int edgeBlocks = (E + TILE - 1) / TILE;
    const int* srcArr = ei;
    const int* dstArr = ei + E;

    encode_kernel<<<nodeBlocks, NTHR, 0, stream>>>(nf, enc_W1, enc_b1, enc_W2,
                                                   enc_b2, h, N);
    for (int l = 0; l < L; ++l) {
        hipMemsetAsync(agg, 0, (size_t)N * H * sizeof(float), stream);
        edge_kernel<<<edgeBlocks, NTHR, 0, stream>>>(
            h, srcArr, dstArr, edge_W1 + (size_t)l * 2 * H * H,
            edge_b1 + (size_t)l * H, edge_W2 + (size_t)l * H * H,
            edge_b2 + (size_t)l * H, agg, E);
        node_kernel<<<nodeBlocks, NTHR, 0, stream>>>(
            h, agg, node_W1 + (size_t)l * 2 * H * H, node_b1 + (size_t)l * H,
            node_W2 + (size_t)l * H * H, node_b2 + (size_t)l * H, N);
    }
    decode_kernel<<<nodeBlocks, NTHR, 0, stream>>>(h, dec_W1, dec_b1, dec_W2,
                                                   dec_b2, (float*)d_out, N);
}

// Round 2
// 2279.239 us; speedup vs baseline: 2.5790x; 2.5790x over previous
//
#include <hip/hip_runtime.h>
#include <math.h>

// FieldlineGraphForecaster round 1: bf16-MFMA edge/node MLPs.
// h kept fp32 (residual master) + bf16 mirror for MFMA gathers.
// Weights converted+transposed to bf16 [col][k] once per launch.
// A tiles staged in LDS with XOR swizzle (^((row&7)<<4)) for conflict-free
// ds_read_b128. MFMA 16x16x32_bf16, fp32 accum. Atomic scatter unchanged.

constexpr int H = 128;
constexpr int NTHR = 256;
constexpr int TE = 64;   // rows per MFMA block tile
constexpr int TILE = 32; // rows per fp32 (enc/dec) tile

using bf16x8 = __attribute__((ext_vector_type(8))) short;
using f32x4  = __attribute__((ext_vector_type(4))) float;

__device__ __forceinline__ float gelu_exact(float x) {
    return 0.5f * x * (1.0f + erff(x * 0.70710678118654752440f));
}

__device__ __forceinline__ unsigned short f2bf(float f) {
    unsigned int u = __builtin_bit_cast(unsigned int, f);
    u = (u + 0x7fffu + ((u >> 16) & 1u)) >> 16;
    return (unsigned short)u;
}

// ------------- weight convert + transpose: W[l][K][N] -> Wt[l][N][K] bf16 --
__global__ __launch_bounds__(NTHR) void wcvt_kernel(
    const float* __restrict__ W, unsigned short* __restrict__ Wt,
    int K, int Ncols, int total) {
    const int i = blockIdx.x * NTHR + threadIdx.x;
    if (i >= total) return;
    const int per = K * Ncols;
    const int l = i / per;
    const int r = i - l * per;
    const int n = r % Ncols;
    const int k = r / Ncols;
    Wt[(size_t)l * per + n * K + k] = f2bf(W[i]);
}

// ===================== MFMA edge-message kernel ===========================
// Per block: 64 edges x 128 cols. 4 waves; wave w owns cols [32w,32w+32).
// Layer1: A = [h_bf[src] | h_bf[dst]] (64x256), W1t (128x256).
// Layer2: A = gelu(L1)+b (64x128, in LDS), W2t (128x128).
// Scatter: atomicAdd into fp32 agg[dst].
__global__ __launch_bounds__(NTHR) void edge_mfma_kernel(
    const unsigned short* __restrict__ h_bf, const int* __restrict__ src,
    const int* __restrict__ dst, const unsigned short* __restrict__ W1t,
    const float* __restrict__ b1, const unsigned short* __restrict__ W2t,
    const float* __restrict__ b2, float* __restrict__ agg, int E) {
    __shared__ __align__(16) unsigned short X[TE * 256];  // 32KB; L2 reuses 16KB
    __shared__ int sIdx[TE], dIdx[TE];
    const int t = threadIdx.x;
    const int lane = t & 63;
    const int w = t >> 6;
    const int e0 = blockIdx.x * TE;
    const int l15 = lane & 15;
    const int lq = lane >> 4;  // quarter-wave id 0..3

    if (t < TE) sIdx[t] = (e0 + t < E) ? src[e0 + t] : 0;
    else if (t < 2 * TE) dIdx[t - TE] = (e0 + t - TE < E) ? dst[e0 + t - TE] : 0;
    __syncthreads();

    // ---- stage A1 (64x256 bf16), 16B chunks, swizzled ----
#pragma unroll
    for (int i = 0; i < 8; ++i) {
        const int c = i * NTHR + t;
        const int row = c >> 5;
        const int col8 = c & 31;                 // 16B chunk within row
        const int col = col8 * 8;
        const int node = (col < 128) ? sIdx[row] : dIdx[row];
        const int4 v = *reinterpret_cast<const int4*>(h_bf + (size_t)node * H + (col & 127));
        const int byteoff = row * 512 + ((col8 * 16) ^ ((row & 7) << 4));
        *reinterpret_cast<int4*>(reinterpret_cast<char*>(X) + byteoff) = v;
    }

    // ---- preload B1 frags (wave-private cols) ----
    bf16x8 B1[2][8];
#pragma unroll
    for (int cg = 0; cg < 2; ++cg) {
        const int col = w * 32 + cg * 16 + l15;
#pragma unroll
        for (int s = 0; s < 8; ++s)
            B1[cg][s] = *reinterpret_cast<const bf16x8*>(
                W1t + (size_t)col * 256 + s * 32 + lq * 8);
    }
    __syncthreads();

    f32x4 acc[4][2];
#pragma unroll
    for (int rg = 0; rg < 4; ++rg)
#pragma unroll
        for (int cg = 0; cg < 2; ++cg) acc[rg][cg] = (f32x4)0.f;

#pragma unroll
    for (int s = 0; s < 8; ++s) {
        bf16x8 a[4];
#pragma unroll
        for (int rg = 0; rg < 4; ++rg) {
            const int row = rg * 16 + l15;
            const int byteoff = row * 512 + ((s * 64 + lq * 16) ^ ((row & 7) << 4));
            a[rg] = *reinterpret_cast<const bf16x8*>(
                reinterpret_cast<const char*>(X) + byteoff);
        }
#pragma unroll
        for (int rg = 0; rg < 4; ++rg)
#pragma unroll
            for (int cg = 0; cg < 2; ++cg)
                acc[rg][cg] = __builtin_amdgcn_mfma_f32_16x16x32_bf16(
                    a[rg], B1[cg][s], acc[rg][cg], 0, 0, 0);
    }
    __syncthreads();  // all waves done reading A1

    // ---- L1 epilogue: bias + GELU -> bf16 -> LDS (64x128, swizzled) ----
#pragma unroll
    for (int cg = 0; cg < 2; ++cg) {
        const int col = w * 32 + cg * 16 + l15;
        const float bb = b1[col];
#pragma unroll
        for (int rg = 0; rg < 4; ++rg) {
#pragma unroll
            for (int r = 0; r < 4; ++r) {
                const int row = rg * 16 + lq * 4 + r;
                const float v = gelu_exact(acc[rg][cg][r] + bb);
                const int byteoff = row * 256 + ((col * 2) ^ ((row & 7) << 4));
                *reinterpret_cast<unsigned short*>(
                    reinterpret_cast<char*>(X) + byteoff) = f2bf(v);
            }
        }
    }

    bf16x8 B2[2][4];
#pragma unroll
    for (int cg = 0; cg < 2; ++cg) {
        const int col = w * 32 + cg * 16 + l15;
#pragma unroll
        for (int s = 0; s < 4; ++s)
            B2[cg][s] = *reinterpret_cast<const bf16x8*>(
                W2t + (size_t)col * 128 + s * 32 + lq * 8);
    }
    __syncthreads();

    f32x4 acc2[4][2];
#pragma unroll
    for (int rg = 0; rg < 4; ++rg)
#pragma unroll
        for (int cg = 0; cg < 2; ++cg) acc2[rg][cg] = (f32x4)0.f;

#pragma unroll
    for (int s = 0; s < 4; ++s) {
        bf16x8 a[4];
#pragma unroll
        for (int rg = 0; rg < 4; ++rg) {
            const int row = rg * 16 + l15;
            const int byteoff = row * 256 + ((s * 64 + lq * 16) ^ ((row & 7) << 4));
            a[rg] = *reinterpret_cast<const bf16x8*>(
                reinterpret_cast<const char*>(X) + byteoff);
        }
#pragma unroll
        for (int rg = 0; rg < 4; ++rg)
#pragma unroll
            for (int cg = 0; cg < 2; ++cg)
                acc2[rg][cg] = __builtin_amdgcn_mfma_f32_16x16x32_bf16(
                    a[rg], B2[cg][s], acc2[rg][cg], 0, 0, 0);
    }

    // ---- scatter: atomicAdd message into agg[dst] ----
#pragma unroll
    for (int cg = 0; cg < 2; ++cg) {
        const int col = w * 32 + cg * 16 + l15;
        const float bb = b2[col];
#pragma unroll
        for (int rg = 0; rg < 4; ++rg) {
#pragma unroll
            for (int r = 0; r < 4; ++r) {
                const int row = rg * 16 + lq * 4 + r;
                if (e0 + row < E) {
                    const int d = dIdx[row];
                    atomicAdd(&agg[(size_t)d * H + col], acc2[rg][cg][r] + bb);
                }
            }
        }
    }
}

// ===================== MFMA node-update kernel ============================
// A = [h_bf[n] | bf16(agg[n])] (64x256). Residual: h += MLP(A).
// Writes h (fp32) and h_bf (bf16).
__global__ __launch_bounds__(NTHR) void node_mfma_kernel(
    float* __restrict__ h, unsigned short* __restrict__ h_bf,
    const float* __restrict__ agg, const unsigned short* __restrict__ W1t,
    const float* __restrict__ b1, const unsigned short* __restrict__ W2t,
    const float* __restrict__ b2, int N) {
    __shared__ __align__(16) unsigned short X[TE * 256];
    const int t = threadIdx.x;
    const int lane = t & 63;
    const int w = t >> 6;
    const int n0 = blockIdx.x * TE;
    const int l15 = lane & 15;
    const int lq = lane >> 4;

#pragma unroll
    for (int i = 0; i < 8; ++i) {
        const int c = i * NTHR + t;
        const int row = c >> 5;
        const int col8 = c & 31;
        const int n = n0 + row;
        int4 v = make_int4(0, 0, 0, 0);
        if (n < N) {
            if (col8 < 16) {
                v = *reinterpret_cast<const int4*>(h_bf + (size_t)n * H + col8 * 8);
            } else {
                const float* ap = agg + (size_t)n * H + (col8 - 16) * 8;
                union { int4 q; unsigned short us[8]; } u;
#pragma unroll
                for (int j = 0; j < 8; ++j) u.us[j] = f2bf(ap[j]);
                v = u.q;
            }
        }
        const int byteoff = row * 512 + ((col8 * 16) ^ ((row & 7) << 4));
        *reinterpret_cast<int4*>(reinterpret_cast<char*>(X) + byteoff) = v;
    }

    bf16x8 B1[2][8];
#pragma unroll
    for (int cg = 0; cg < 2; ++cg) {
        const int col = w * 32 + cg * 16 + l15;
#pragma unroll
        for (int s = 0; s < 8; ++s)
            B1[cg][s] = *reinterpret_cast<const bf16x8*>(
                W1t + (size_t)col * 256 + s * 32 + lq * 8);
    }
    __syncthreads();

    f32x4 acc[4][2];
#pragma unroll
    for (int rg = 0; rg < 4; ++rg)
#pragma unroll
        for (int cg = 0; cg < 2; ++cg) acc[rg][cg] = (f32x4)0.f;

#pragma unroll
    for (int s = 0; s < 8; ++s) {
        bf16x8 a[4];
#pragma unroll
        for (int rg = 0; rg < 4; ++rg) {
            const int row = rg * 16 + l15;
            const int byteoff = row * 512 + ((s * 64 + lq * 16) ^ ((row & 7) << 4));
            a[rg] = *reinterpret_cast<const bf16x8*>(
                reinterpret_cast<const char*>(X) + byteoff);
        }
#pragma unroll
        for (int rg = 0; rg < 4; ++rg)
#pragma unroll
            for (int cg = 0; cg < 2; ++cg)
                acc[rg][cg] = __builtin_amdgcn_mfma_f32_16x16x32_bf16(
                    a[rg], B1[cg][s], acc[rg][cg], 0, 0, 0);
    }
    __syncthreads();

#pragma unroll
    for (int cg = 0; cg < 2; ++cg) {
        const int col = w * 32 + cg * 16 + l15;
        const float bb = b1[col];
#pragma unroll
        for (int rg = 0; rg < 4; ++rg) {
#pragma unroll
            for (int r = 0; r < 4; ++r) {
                const int row = rg * 16 + lq * 4 + r;
                const float v = gelu_exact(acc[rg][cg][r] + bb);
                const int byteoff = row * 256 + ((col * 2) ^ ((row & 7) << 4));
                *reinterpret_cast<unsigned short*>(
                    reinterpret_cast<char*>(X) + byteoff) = f2bf(v);
            }
        }
    }

    bf16x8 B2[2][4];
#pragma unroll
    for (int cg = 0; cg < 2; ++cg) {
        const int col = w * 32 + cg * 16 + l15;
#pragma unroll
        for (int s = 0; s < 4; ++s)
            B2[cg][s] = *reinterpret_cast<const bf16x8*>(
                W2t + (size_t)col * 128 + s * 32 + lq * 8);
    }
    __syncthreads();

    f32x4 acc2[4][2];
#pragma unroll
    for (int rg = 0; rg < 4; ++rg)
#pragma unroll
        for (int cg = 0; cg < 2; ++cg) acc2[rg][cg] = (f32x4)0.f;

#pragma unroll
    for (int s = 0; s < 4; ++s) {
        bf16x8 a[4];
#pragma unroll
        for (int rg = 0; rg < 4; ++rg) {
            const int row = rg * 16 + l15;
            const int byteoff = row * 256 + ((s * 64 + lq * 16) ^ ((row & 7) << 4));
            a[rg] = *reinterpret_cast<const bf16x8*>(
                reinterpret_cast<const char*>(X) + byteoff);
        }
#pragma unroll
        for (int rg = 0; rg < 4; ++rg)
#pragma unroll
            for (int cg = 0; cg < 2; ++cg)
                acc2[rg][cg] = __builtin_amdgcn_mfma_f32_16x16x32_bf16(
                    a[rg], B2[cg][s], acc2[rg][cg], 0, 0, 0);
    }

    // residual write: h += update; refresh bf16 mirror
#pragma unroll
    for (int cg = 0; cg < 2; ++cg) {
        const int col = w * 32 + cg * 16 + l15;
        const float bb = b2[col];
#pragma unroll
        for (int rg = 0; rg < 4; ++rg) {
#pragma unroll
            for (int r = 0; r < 4; ++r) {
                const int row = rg * 16 + lq * 4 + r;
                const int n = n0 + row;
                if (n < N) {
                    const float hv = h[(size_t)n * H + col] + acc2[rg][cg][r] + bb;
                    h[(size_t)n * H + col] = hv;
                    h_bf[(size_t)n * H + col] = f2bf(hv);
                }
            }
        }
    }
}

// ---------------- fp32 helper for encoder/decoder -------------------------
template <int K4>
__device__ __forceinline__ void mlp_layer(const float* __restrict__ W,
                                          const float* lds, int ldsStride,
                                          int c0, int egBase,
                                          float a0[8], float a1[8]) {
#pragma unroll 2
    for (int k4 = 0; k4 < K4; ++k4) {
        const float w00 = W[(k4 * 4 + 0) * H + c0];
        const float w01 = W[(k4 * 4 + 1) * H + c0];
        const float w02 = W[(k4 * 4 + 2) * H + c0];
        const float w03 = W[(k4 * 4 + 3) * H + c0];
        const float w10 = W[(k4 * 4 + 0) * H + c0 + 64];
        const float w11 = W[(k4 * 4 + 1) * H + c0 + 64];
        const float w12 = W[(k4 * 4 + 2) * H + c0 + 64];
        const float w13 = W[(k4 * 4 + 3) * H + c0 + 64];
#pragma unroll
        for (int e = 0; e < 8; ++e) {
            const float4 x = *reinterpret_cast<const float4*>(
                &lds[(egBase + e) * ldsStride + k4 * 4]);
            a0[e] = fmaf(x.x, w00, a0[e]);
            a0[e] = fmaf(x.y, w01, a0[e]);
            a0[e] = fmaf(x.z, w02, a0[e]);
            a0[e] = fmaf(x.w, w03, a0[e]);
            a1[e] = fmaf(x.x, w10, a1[e]);
            a1[e] = fmaf(x.y, w11, a1[e]);
            a1[e] = fmaf(x.z, w12, a1[e]);
            a1[e] = fmaf(x.w, w13, a1[e]);
        }
    }
}

// ---------------- encoder: [N,16] -> MLP -> h fp32 + h_bf bf16 ------------
__global__ __launch_bounds__(NTHR) void encode_kernel(
    const float* __restrict__ nf, const float* __restrict__ W1,
    const float* __restrict__ b1, const float* __restrict__ W2,
    const float* __restrict__ b2, float* __restrict__ h,
    unsigned short* __restrict__ h_bf, int N) {
    __shared__ float xin[TILE * 16];
    __shared__ float hm[TILE * H];
    const int t = threadIdx.x;
    const int n0 = blockIdx.x * TILE;
    const int c0 = t & 63;
    const int eg = t >> 6;

    for (int i = t; i < TILE * 16; i += NTHR) {
        const int gi = n0 * 16 + i;
        xin[i] = (gi < N * 16) ? nf[gi] : 0.f;
    }
    __syncthreads();

    float a0[8], a1[8];
#pragma unroll
    for (int e = 0; e < 8; ++e) { a0[e] = 0.f; a1[e] = 0.f; }
    mlp_layer<4>(W1, xin, 16, c0, eg * 8, a0, a1);
    {
        const float bb0 = b1[c0], bb1 = b1[c0 + 64];
#pragma unroll
        for (int e = 0; e < 8; ++e) {
            hm[(eg * 8 + e) * H + c0] = gelu_exact(a0[e] + bb0);
            hm[(eg * 8 + e) * H + c0 + 64] = gelu_exact(a1[e] + bb1);
        }
    }
    __syncthreads();
#pragma unroll
    for (int e = 0; e < 8; ++e) { a0[e] = 0.f; a1[e] = 0.f; }
    mlp_layer<32>(W2, hm, H, c0, eg * 8, a0, a1);
    const float bb0 = b2[c0], bb1 = b2[c0 + 64];
#pragma unroll
    for (int e = 0; e < 8; ++e) {
        const int n = n0 + eg * 8 + e;
        if (n < N) {
            const float v0 = a0[e] + bb0, v1 = a1[e] + bb1;
            h[(size_t)n * H + c0] = v0;
            h[(size_t)n * H + c0 + 64] = v1;
            h_bf[(size_t)n * H + c0] = f2bf(v0);
            h_bf[(size_t)n * H + c0 + 64] = f2bf(v1);
        }
    }
}

// --------------- decoder: h -> GELU MLP -> out [N,8] ----------------------
__global__ __launch_bounds__(NTHR) void decode_kernel(
    const float* __restrict__ h, const float* __restrict__ W1,
    const float* __restrict__ b1, const float* __restrict__ W2,
    const float* __restrict__ b2, float* __restrict__ out, int N) {
    __shared__ float xin[TILE * H];
    __shared__ float hm[TILE * 132];
    const int t = threadIdx.x;
    const int n0 = blockIdx.x * TILE;
    const int c0 = t & 63;
    const int eg = t >> 6;
    {
        const int col = t & 127;
        for (int e = t >> 7; e < TILE; e += 2) {
            const int n = n0 + e;
            xin[e * H + col] = (n < N) ? h[(size_t)n * H + col] : 0.f;
        }
    }
    __syncthreads();

    float a0[8], a1[8];
#pragma unroll
    for (int e = 0; e < 8; ++e) { a0[e] = 0.f; a1[e] = 0.f; }
    mlp_layer<32>(W1, xin, H, c0, eg * 8, a0, a1);
    {
        const float bb0 = b1[c0], bb1 = b1[c0 + 64];
#pragma unroll
        for (int e = 0; e < 8; ++e) {
            hm[(eg * 8 + e) * 132 + c0] = gelu_exact(a0[e] + bb0);
            hm[(eg * 8 + e) * 132 + c0 + 64] = gelu_exact(a1[e] + bb1);
        }
    }
    __syncthreads();
    {
        const int e = t >> 3;
        const int o = t & 7;
        const int n = n0 + e;
        float acc = b2[o];
#pragma unroll 4
        for (int k = 0; k < H; ++k)
            acc = fmaf(hm[e * 132 + k], W2[k * 8 + o], acc);
        if (n < N) out[n * 8 + o] = acc;
    }
}

extern "C" void kernel_launch(void* const* d_in, const int* in_sizes, int n_in,
                              void* d_out, int out_size, void* d_ws,
                              size_t ws_size, hipStream_t stream) {
    (void)n_in; (void)out_size; (void)ws_size;
    const float* nf      = (const float*)d_in[0];
    const int*   ei      = (const int*)d_in[1];
    const float* enc_W1  = (const float*)d_in[2];
    const float* enc_b1  = (const float*)d_in[3];
    const float* enc_W2  = (const float*)d_in[4];
    const float* enc_b2  = (const float*)d_in[5];
    const float* edge_W1 = (const float*)d_in[6];
    const float* edge_b1 = (const float*)d_in[7];
    const float* edge_W2 = (const float*)d_in[8];
    const float* edge_b2 = (const float*)d_in[9];
    const float* node_W1 = (const float*)d_in[10];
    const float* node_b1 = (const float*)d_in[11];
    const float* node_W2 = (const float*)d_in[12];
    const float* node_b2 = (const float*)d_in[13];
    const float* dec_W1  = (const float*)d_in[14];
    const float* dec_b1  = (const float*)d_in[15];
    const float* dec_W2  = (const float*)d_in[16];
    const float* dec_b2  = (const float*)d_in[17];

    const int N = in_sizes[0] / 16;
    const int E = in_sizes[1] / 2;
    const int L = in_sizes[7] / H;  // edge_b1 is [L,H]

    // workspace layout
    char* ws = (char*)d_ws;
    float* h   = (float*)ws;                          ws += (size_t)N * H * 4;
    float* agg = (float*)ws;                          ws += (size_t)N * H * 4;
    unsigned short* h_bf = (unsigned short*)ws;       ws += (size_t)N * H * 2;
    unsigned short* eW1t = (unsigned short*)ws;       ws += (size_t)L * 2 * H * H * 2;
    unsigned short* eW2t = (unsigned short*)ws;       ws += (size_t)L * H * H * 2;
    unsigned short* nW1t = (unsigned short*)ws;       ws += (size_t)L * 2 * H * H * 2;
    unsigned short* nW2t = (unsigned short*)ws;       ws += (size_t)L * H * H * 2;

    const int* srcArr = ei;
    const int* dstArr = ei + E;

    // weight conversion (tiny, once per launch/replay)
    {
        const int t1 = L * 2 * H * H, t2 = L * H * H;
        wcvt_kernel<<<(t1 + NTHR - 1) / NTHR, NTHR, 0, stream>>>(edge_W1, eW1t, 2 * H, H, t1);
        wcvt_kernel<<<(t2 + NTHR - 1) / NTHR, NTHR, 0, stream>>>(edge_W2, eW2t, H, H, t2);
        wcvt_kernel<<<(t1 + NTHR - 1) / NTHR, NTHR, 0, stream>>>(node_W1, nW1t, 2 * H, H, t1);
        wcvt_kernel<<<(t2 + NTHR - 1) / NTHR, NTHR, 0, stream>>>(node_W2, nW2t, H, H, t2);
    }

    const int encBlocks  = (N + TILE - 1) / TILE;
    const int nodeBlocks = (N + TE - 1) / TE;
    const int edgeBlocks = (E + TE - 1) / TE;

    encode_kernel<<<encBlocks, NTHR, 0, stream>>>(nf, enc_W1, enc_b1, enc_W2,
                                                  enc_b2, h, h_bf, N);
    for (int l = 0; l < L; ++l) {
        hipMemsetAsync(agg, 0, (size_t)N * H * sizeof(float), stream);
        edge_mfma_kernel<<<edgeBlocks, NTHR, 0, stream>>>(
            h_bf, srcArr, dstArr, eW1t + (size_t)l * 2 * H * H,
            edge_b1 + (size_t)l * H, eW2t + (size_t)l * H * H,
            edge_b2 + (size_t)l * H, agg, E);
        node_mfma_kernel<<<nodeBlocks, NTHR, 0, stream>>>(
            h, h_bf, agg, nW1t + (size_t)l * 2 * H * H, node_b1 + (size_t)l * H,
            nW2t + (size_t)l * H * H, node_b2 + (size_t)l * H, N);
    }
    decode_kernel<<<encBlocks, NTHR, 0, stream>>>(h, dec_W1, dec_b1, dec_W2,
                                                  dec_b2, (float*)d_out, N);
}

// Round 3
// 1017.378 us; speedup vs baseline: 5.7778x; 2.2403x over previous
//
#include <hip/hip_runtime.h>
#include <math.h>

// FieldlineGraphForecaster round 2: algebraic restructure.
//   A = h@W1_top (bf16), B = h@W1_bot + b1 (fp32)   [dense, per node]
//   per edge: g = GELU(A[src] + B[dst]); run-sum over dst-sorted edges
//   aggregated = aggG@W2 + deg*b2                     [dense, per node]
//   node update MLP unchanged (MFMA).
// Edges sorted by dst once per launch (hist+scan+scatter) -> atomics 10x down.

constexpr int H = 128;
constexpr int NTHR = 256;
constexpr int TE = 64;    // rows per MFMA tile
constexpr int TILE = 32;  // rows per fp32 (enc/dec) tile
constexpr int CHUNK = 32; // sorted edges per wave

using bf16x8 = __attribute__((ext_vector_type(8))) short;
using f32x4  = __attribute__((ext_vector_type(4))) float;

__device__ __forceinline__ float gelu_exact(float x) {
    return 0.5f * x * (1.0f + erff(x * 0.70710678118654752440f));
}

__device__ __forceinline__ unsigned short f2bf(float f) {
    unsigned int u = __builtin_bit_cast(unsigned int, f);
    u = (u + 0x7fffu + ((u >> 16) & 1u)) >> 16;
    return (unsigned short)u;
}

__device__ __forceinline__ float bf2f_lo(unsigned int v) {
    return __builtin_bit_cast(float, v << 16);
}
__device__ __forceinline__ float bf2f_hi(unsigned int v) {
    return __builtin_bit_cast(float, v & 0xffff0000u);
}

// ---------- weight convert+transpose: W[l][K][N] -> Wt[l][N][K] bf16 ------
__global__ __launch_bounds__(NTHR) void wcvt_kernel(
    const float* __restrict__ W, unsigned short* __restrict__ Wt,
    int K, int Ncols, int total) {
    const int i = blockIdx.x * NTHR + threadIdx.x;
    if (i >= total) return;
    const int per = K * Ncols;
    const int l = i / per;
    const int r = i - l * per;
    const int n = r % Ncols;
    const int k = r / Ncols;
    Wt[(size_t)l * per + n * K + k] = f2bf(W[i]);
}

// ----------------------- sort-by-dst machinery ----------------------------
__global__ __launch_bounds__(NTHR) void deg_kernel(const int* __restrict__ dst,
                                                   int* __restrict__ deg, int E) {
    const int e = blockIdx.x * NTHR + threadIdx.x;
    if (e < E) atomicAdd(&deg[dst[e]], 1);
}

__global__ __launch_bounds__(1024) void scan_kernel(const int* __restrict__ deg,
                                                    int* __restrict__ rowStart,
                                                    int N) {
    __shared__ int buf[1024];
    __shared__ int carry;
    const int t = threadIdx.x;
    if (t == 0) carry = 0;
    __syncthreads();
    for (int base = 0; base < N; base += 1024) {
        const int x = (base + t < N) ? deg[base + t] : 0;
        buf[t] = x;
        __syncthreads();
        int v = x;
        for (int off = 1; off < 1024; off <<= 1) {
            const int y = (t >= off) ? buf[t - off] : 0;
            __syncthreads();
            v += y;
            buf[t] = v;
            __syncthreads();
        }
        if (base + t < N) rowStart[base + t] = carry + v - x;  // exclusive
        __syncthreads();
        if (t == 0) carry += buf[1023];
        __syncthreads();
    }
}

__global__ __launch_bounds__(NTHR) void copy_kernel(const int* __restrict__ a,
                                                    int* __restrict__ b, int n) {
    const int i = blockIdx.x * NTHR + threadIdx.x;
    if (i < n) b[i] = a[i];
}

__global__ __launch_bounds__(NTHR) void scatter_kernel(
    const int* __restrict__ src, const int* __restrict__ dst,
    int* __restrict__ cursor, int* __restrict__ srcS, int* __restrict__ dstS,
    int E) {
    const int e = blockIdx.x * NTHR + threadIdx.x;
    if (e >= E) return;
    const int d = dst[e];
    const int pos = atomicAdd(&cursor[d], 1);
    srcS[pos] = src[e];
    dstS[pos] = d;
}

// ---- A/B kernel: A = h@W1_top (bf16), B = h@W1_bot + b1 (fp32) -----------
// 64 node rows per block; wave w: half=w>>1 (0:A,1:B), cols (w&1)*64 .. +63.
__global__ __launch_bounds__(NTHR) void ab_kernel(
    const unsigned short* __restrict__ h_bf,
    const unsigned short* __restrict__ W1t,  // [128 cols][256 k]
    const float* __restrict__ b1, unsigned short* __restrict__ A,
    float* __restrict__ Bout, int N) {
    __shared__ __align__(16) unsigned short X[TE * H];  // 16KB
    const int t = threadIdx.x;
    const int lane = t & 63;
    const int w = t >> 6;
    const int n0 = blockIdx.x * TE;
    const int l15 = lane & 15;
    const int lq = lane >> 4;

#pragma unroll
    for (int i = 0; i < 4; ++i) {
        const int c = i * NTHR + t;
        const int row = c >> 4;
        const int col8 = c & 15;
        const int n = n0 + row;
        const int4 v = (n < N)
            ? *reinterpret_cast<const int4*>(h_bf + (size_t)n * H + col8 * 8)
            : make_int4(0, 0, 0, 0);
        const int byteoff = row * 256 + ((col8 * 16) ^ ((row & 7) << 4));
        *reinterpret_cast<int4*>(reinterpret_cast<char*>(X) + byteoff) = v;
    }

    const int half = w >> 1;             // 0 -> A (k 0..127), 1 -> B (k 128..255)
    const int cbase = (w & 1) * 64;
    bf16x8 Bf[4][4];
#pragma unroll
    for (int cg = 0; cg < 4; ++cg) {
        const int col = cbase + cg * 16 + l15;
#pragma unroll
        for (int s = 0; s < 4; ++s)
            Bf[cg][s] = *reinterpret_cast<const bf16x8*>(
                W1t + (size_t)col * 256 + half * 128 + s * 32 + lq * 8);
    }
    __syncthreads();

    f32x4 acc[4][4];
#pragma unroll
    for (int rg = 0; rg < 4; ++rg)
#pragma unroll
        for (int cg = 0; cg < 4; ++cg) acc[rg][cg] = (f32x4)0.f;

#pragma unroll
    for (int s = 0; s < 4; ++s) {
        bf16x8 a[4];
#pragma unroll
        for (int rg = 0; rg < 4; ++rg) {
            const int row = rg * 16 + l15;
            const int byteoff = row * 256 + ((s * 64 + lq * 16) ^ ((row & 7) << 4));
            a[rg] = *reinterpret_cast<const bf16x8*>(
                reinterpret_cast<const char*>(X) + byteoff);
        }
#pragma unroll
        for (int rg = 0; rg < 4; ++rg)
#pragma unroll
            for (int cg = 0; cg < 4; ++cg)
                acc[rg][cg] = __builtin_amdgcn_mfma_f32_16x16x32_bf16(
                    a[rg], Bf[cg][s], acc[rg][cg], 0, 0, 0);
    }

#pragma unroll
    for (int cg = 0; cg < 4; ++cg) {
        const int col = cbase + cg * 16 + l15;
        const float bb = (half == 1) ? b1[col] : 0.f;
#pragma unroll
        for (int rg = 0; rg < 4; ++rg) {
#pragma unroll
            for (int r = 0; r < 4; ++r) {
                const int row = rg * 16 + lq * 4 + r;
                const int n = n0 + row;
                if (n < N) {
                    if (half == 0)
                        A[(size_t)n * H + col] = f2bf(acc[rg][cg][r]);
                    else
                        Bout[(size_t)n * H + col] = acc[rg][cg][r] + bb;
                }
            }
        }
    }
}

// ---- edge gather: per wave, 32 dst-sorted edges; run-sum then atomic -----
__global__ __launch_bounds__(NTHR) void edge_gather_kernel(
    const unsigned short* __restrict__ A, const float* __restrict__ B,
    const int* __restrict__ srcS, const int* __restrict__ dstS,
    float* __restrict__ aggG, int E) {
    const int lane = threadIdx.x & 63;
    const int wave = blockIdx.x * 4 + (threadIdx.x >> 6);
    const int e0 = wave * CHUNK;
    if (e0 >= E) return;  // wave-uniform
    const int c2 = lane * 2;
    const int cnt = min(CHUNK, E - e0);

    int sI = 0, dI = 0;
    if (lane < CHUNK && e0 + lane < E) {
        sI = srcS[e0 + lane];
        dI = dstS[e0 + lane];
    }

    int curd = -1;
    float s0 = 0.f, s1 = 0.f, B0 = 0.f, B1 = 0.f;
#pragma unroll 4
    for (int i = 0; i < cnt; ++i) {
        const int s = __shfl(sI, i);
        const int d = __shfl(dI, i);
        if (d != curd) {  // wave-uniform branch
            if (curd >= 0) {
                atomicAdd(&aggG[(size_t)curd * H + c2], s0);
                atomicAdd(&aggG[(size_t)curd * H + c2 + 1], s1);
            }
            s0 = s1 = 0.f;
            curd = d;
            const float2 bv =
                *reinterpret_cast<const float2*>(B + (size_t)d * H + c2);
            B0 = bv.x;
            B1 = bv.y;
        }
        const unsigned int av =
            *reinterpret_cast<const unsigned int*>(A + (size_t)s * H + c2);
        s0 += gelu_exact(bf2f_lo(av) + B0);
        s1 += gelu_exact(bf2f_hi(av) + B1);
    }
    if (curd >= 0) {
        atomicAdd(&aggG[(size_t)curd * H + c2], s0);
        atomicAdd(&aggG[(size_t)curd * H + c2 + 1], s1);
    }
}

// ---- aggregated = aggG@W2 + deg*b2 -> bf16 -------------------------------
__global__ __launch_bounds__(NTHR) void aggw2_kernel(
    const float* __restrict__ aggG, const unsigned short* __restrict__ W2t,
    const float* __restrict__ b2, const int* __restrict__ deg,
    unsigned short* __restrict__ aggB, int N) {
    __shared__ __align__(16) unsigned short X[TE * H];
    __shared__ int degS[TE];
    const int t = threadIdx.x;
    const int lane = t & 63;
    const int w = t >> 6;
    const int n0 = blockIdx.x * TE;
    const int l15 = lane & 15;
    const int lq = lane >> 4;

    if (t < TE) degS[t] = (n0 + t < N) ? deg[n0 + t] : 0;
#pragma unroll
    for (int i = 0; i < 4; ++i) {
        const int c = i * NTHR + t;
        const int row = c >> 4;
        const int col8 = c & 15;
        const int n = n0 + row;
        union { int4 q; unsigned short us[8]; } u;
        if (n < N) {
            const float4 f0 = *reinterpret_cast<const float4*>(
                aggG + (size_t)n * H + col8 * 8);
            const float4 f1 = *reinterpret_cast<const float4*>(
                aggG + (size_t)n * H + col8 * 8 + 4);
            u.us[0] = f2bf(f0.x); u.us[1] = f2bf(f0.y);
            u.us[2] = f2bf(f0.z); u.us[3] = f2bf(f0.w);
            u.us[4] = f2bf(f1.x); u.us[5] = f2bf(f1.y);
            u.us[6] = f2bf(f1.z); u.us[7] = f2bf(f1.w);
        } else {
            u.q = make_int4(0, 0, 0, 0);
        }
        const int byteoff = row * 256 + ((col8 * 16) ^ ((row & 7) << 4));
        *reinterpret_cast<int4*>(reinterpret_cast<char*>(X) + byteoff) = u.q;
    }

    bf16x8 Bf[2][4];
#pragma unroll
    for (int cg = 0; cg < 2; ++cg) {
        const int col = w * 32 + cg * 16 + l15;
#pragma unroll
        for (int s = 0; s < 4; ++s)
            Bf[cg][s] = *reinterpret_cast<const bf16x8*>(
                W2t + (size_t)col * 128 + s * 32 + lq * 8);
    }
    __syncthreads();

    f32x4 acc[4][2];
#pragma unroll
    for (int rg = 0; rg < 4; ++rg)
#pragma unroll
        for (int cg = 0; cg < 2; ++cg) acc[rg][cg] = (f32x4)0.f;

#pragma unroll
    for (int s = 0; s < 4; ++s) {
        bf16x8 a[4];
#pragma unroll
        for (int rg = 0; rg < 4; ++rg) {
            const int row = rg * 16 + l15;
            const int byteoff = row * 256 + ((s * 64 + lq * 16) ^ ((row & 7) << 4));
            a[rg] = *reinterpret_cast<const bf16x8*>(
                reinterpret_cast<const char*>(X) + byteoff);
        }
#pragma unroll
        for (int rg = 0; rg < 4; ++rg)
#pragma unroll
            for (int cg = 0; cg < 2; ++cg)
                acc[rg][cg] = __builtin_amdgcn_mfma_f32_16x16x32_bf16(
                    a[rg], Bf[cg][s], acc[rg][cg], 0, 0, 0);
    }

#pragma unroll
    for (int cg = 0; cg < 2; ++cg) {
        const int col = w * 32 + cg * 16 + l15;
        const float bb = b2[col];
#pragma unroll
        for (int rg = 0; rg < 4; ++rg) {
#pragma unroll
            for (int r = 0; r < 4; ++r) {
                const int row = rg * 16 + lq * 4 + r;
                const int n = n0 + row;
                if (n < N)
                    aggB[(size_t)n * H + col] =
                        f2bf(acc[rg][cg][r] + (float)degS[row] * bb);
            }
        }
    }
}

// ---- node update: h += MLP([h | aggregated]) (MFMA), refresh h_bf --------
__global__ __launch_bounds__(NTHR) void node_mfma_kernel(
    float* __restrict__ h, unsigned short* __restrict__ h_bf,
    const unsigned short* __restrict__ aggB,
    const unsigned short* __restrict__ W1t, const float* __restrict__ b1,
    const unsigned short* __restrict__ W2t, const float* __restrict__ b2,
    int N) {
    __shared__ __align__(16) unsigned short X[TE * 256];
    const int t = threadIdx.x;
    const int lane = t & 63;
    const int w = t >> 6;
    const int n0 = blockIdx.x * TE;
    const int l15 = lane & 15;
    const int lq = lane >> 4;

#pragma unroll
    for (int i = 0; i < 8; ++i) {
        const int c = i * NTHR + t;
        const int row = c >> 5;
        const int col8 = c & 31;
        const int n = n0 + row;
        int4 v = make_int4(0, 0, 0, 0);
        if (n < N) {
            v = (col8 < 16)
                ? *reinterpret_cast<const int4*>(h_bf + (size_t)n * H + col8 * 8)
                : *reinterpret_cast<const int4*>(aggB + (size_t)n * H +
                                                 (col8 - 16) * 8);
        }
        const int byteoff = row * 512 + ((col8 * 16) ^ ((row & 7) << 4));
        *reinterpret_cast<int4*>(reinterpret_cast<char*>(X) + byteoff) = v;
    }

    bf16x8 B1[2][8];
#pragma unroll
    for (int cg = 0; cg < 2; ++cg) {
        const int col = w * 32 + cg * 16 + l15;
#pragma unroll
        for (int s = 0; s < 8; ++s)
            B1[cg][s] = *reinterpret_cast<const bf16x8*>(
                W1t + (size_t)col * 256 + s * 32 + lq * 8);
    }
    __syncthreads();

    f32x4 acc[4][2];
#pragma unroll
    for (int rg = 0; rg < 4; ++rg)
#pragma unroll
        for (int cg = 0; cg < 2; ++cg) acc[rg][cg] = (f32x4)0.f;

#pragma unroll
    for (int s = 0; s < 8; ++s) {
        bf16x8 a[4];
#pragma unroll
        for (int rg = 0; rg < 4; ++rg) {
            const int row = rg * 16 + l15;
            const int byteoff = row * 512 + ((s * 64 + lq * 16) ^ ((row & 7) << 4));
            a[rg] = *reinterpret_cast<const bf16x8*>(
                reinterpret_cast<const char*>(X) + byteoff);
        }
#pragma unroll
        for (int rg = 0; rg < 4; ++rg)
#pragma unroll
            for (int cg = 0; cg < 2; ++cg)
                acc[rg][cg] = __builtin_amdgcn_mfma_f32_16x16x32_bf16(
                    a[rg], B1[cg][s], acc[rg][cg], 0, 0, 0);
    }
    __syncthreads();

#pragma unroll
    for (int cg = 0; cg < 2; ++cg) {
        const int col = w * 32 + cg * 16 + l15;
        const float bb = b1[col];
#pragma unroll
        for (int rg = 0; rg < 4; ++rg) {
#pragma unroll
            for (int r = 0; r < 4; ++r) {
                const int row = rg * 16 + lq * 4 + r;
                const float v = gelu_exact(acc[rg][cg][r] + bb);
                const int byteoff = row * 256 + ((col * 2) ^ ((row & 7) << 4));
                *reinterpret_cast<unsigned short*>(
                    reinterpret_cast<char*>(X) + byteoff) = f2bf(v);
            }
        }
    }

    bf16x8 B2[2][4];
#pragma unroll
    for (int cg = 0; cg < 2; ++cg) {
        const int col = w * 32 + cg * 16 + l15;
#pragma unroll
        for (int s = 0; s < 4; ++s)
            B2[cg][s] = *reinterpret_cast<const bf16x8*>(
                W2t + (size_t)col * 128 + s * 32 + lq * 8);
    }
    __syncthreads();

    f32x4 acc2[4][2];
#pragma unroll
    for (int rg = 0; rg < 4; ++rg)
#pragma unroll
        for (int cg = 0; cg < 2; ++cg) acc2[rg][cg] = (f32x4)0.f;

#pragma unroll
    for (int s = 0; s < 4; ++s) {
        bf16x8 a[4];
#pragma unroll
        for (int rg = 0; rg < 4; ++rg) {
            const int row = rg * 16 + l15;
            const int byteoff = row * 256 + ((s * 64 + lq * 16) ^ ((row & 7) << 4));
            a[rg] = *reinterpret_cast<const bf16x8*>(
                reinterpret_cast<const char*>(X) + byteoff);
        }
#pragma unroll
        for (int rg = 0; rg < 4; ++rg)
#pragma unroll
            for (int cg = 0; cg < 2; ++cg)
                acc2[rg][cg] = __builtin_amdgcn_mfma_f32_16x16x32_bf16(
                    a[rg], B2[cg][s], acc2[rg][cg], 0, 0, 0);
    }

#pragma unroll
    for (int cg = 0; cg < 2; ++cg) {
        const int col = w * 32 + cg * 16 + l15;
        const float bb = b2[col];
#pragma unroll
        for (int rg = 0; rg < 4; ++rg) {
#pragma unroll
            for (int r = 0; r < 4; ++r) {
                const int row = rg * 16 + lq * 4 + r;
                const int n = n0 + row;
                if (n < N) {
                    const float hv = h[(size_t)n * H + col] + acc2[rg][cg][r] + bb;
                    h[(size_t)n * H + col] = hv;
                    h_bf[(size_t)n * H + col] = f2bf(hv);
                }
            }
        }
    }
}

// ---------------- fp32 helper for encoder/decoder -------------------------
template <int K4>
__device__ __forceinline__ void mlp_layer(const float* __restrict__ W,
                                          const float* lds, int ldsStride,
                                          int c0, int egBase,
                                          float a0[8], float a1[8]) {
#pragma unroll 2
    for (int k4 = 0; k4 < K4; ++k4) {
        const float w00 = W[(k4 * 4 + 0) * H + c0];
        const float w01 = W[(k4 * 4 + 1) * H + c0];
        const float w02 = W[(k4 * 4 + 2) * H + c0];
        const float w03 = W[(k4 * 4 + 3) * H + c0];
        const float w10 = W[(k4 * 4 + 0) * H + c0 + 64];
        const float w11 = W[(k4 * 4 + 1) * H + c0 + 64];
        const float w12 = W[(k4 * 4 + 2) * H + c0 + 64];
        const float w13 = W[(k4 * 4 + 3) * H + c0 + 64];
#pragma unroll
        for (int e = 0; e < 8; ++e) {
            const float4 x = *reinterpret_cast<const float4*>(
                &lds[(egBase + e) * ldsStride + k4 * 4]);
            a0[e] = fmaf(x.x, w00, a0[e]);
            a0[e] = fmaf(x.y, w01, a0[e]);
            a0[e] = fmaf(x.z, w02, a0[e]);
            a0[e] = fmaf(x.w, w03, a0[e]);
            a1[e] = fmaf(x.x, w10, a1[e]);
            a1[e] = fmaf(x.y, w11, a1[e]);
            a1[e] = fmaf(x.z, w12, a1[e]);
            a1[e] = fmaf(x.w, w13, a1[e]);
        }
    }
}

// ---------------- encoder: [N,16] -> MLP -> h fp32 + h_bf bf16 ------------
__global__ __launch_bounds__(NTHR) void encode_kernel(
    const float* __restrict__ nf, const float* __restrict__ W1,
    const float* __restrict__ b1, const float* __restrict__ W2,
    const float* __restrict__ b2, float* __restrict__ h,
    unsigned short* __restrict__ h_bf, int N) {
    __shared__ float xin[TILE * 16];
    __shared__ float hm[TILE * H];
    const int t = threadIdx.x;
    const int n0 = blockIdx.x * TILE;
    const int c0 = t & 63;
    const int eg = t >> 6;

    for (int i = t; i < TILE * 16; i += NTHR) {
        const int gi = n0 * 16 + i;
        xin[i] = (gi < N * 16) ? nf[gi] : 0.f;
    }
    __syncthreads();

    float a0[8], a1[8];
#pragma unroll
    for (int e = 0; e < 8; ++e) { a0[e] = 0.f; a1[e] = 0.f; }
    mlp_layer<4>(W1, xin, 16, c0, eg * 8, a0, a1);
    {
        const float bb0 = b1[c0], bb1 = b1[c0 + 64];
#pragma unroll
        for (int e = 0; e < 8; ++e) {
            hm[(eg * 8 + e) * H + c0] = gelu_exact(a0[e] + bb0);
            hm[(eg * 8 + e) * H + c0 + 64] = gelu_exact(a1[e] + bb1);
        }
    }
    __syncthreads();
#pragma unroll
    for (int e = 0; e < 8; ++e) { a0[e] = 0.f; a1[e] = 0.f; }
    mlp_layer<32>(W2, hm, H, c0, eg * 8, a0, a1);
    const float bb0 = b2[c0], bb1 = b2[c0 + 64];
#pragma unroll
    for (int e = 0; e < 8; ++e) {
        const int n = n0 + eg * 8 + e;
        if (n < N) {
            const float v0 = a0[e] + bb0, v1 = a1[e] + bb1;
            h[(size_t)n * H + c0] = v0;
            h[(size_t)n * H + c0 + 64] = v1;
            h_bf[(size_t)n * H + c0] = f2bf(v0);
            h_bf[(size_t)n * H + c0 + 64] = f2bf(v1);
        }
    }
}

// --------------- decoder: h -> GELU MLP -> out [N,8] ----------------------
__global__ __launch_bounds__(NTHR) void decode_kernel(
    const float* __restrict__ h, const float* __restrict__ W1,
    const float* __restrict__ b1, const float* __restrict__ W2,
    const float* __restrict__ b2, float* __restrict__ out, int N) {
    __shared__ float xin[TILE * H];
    __shared__ float hm[TILE * 132];
    const int t = threadIdx.x;
    const int n0 = blockIdx.x * TILE;
    const int c0 = t & 63;
    const int eg = t >> 6;
    {
        const int col = t & 127;
        for (int e = t >> 7; e < TILE; e += 2) {
            const int n = n0 + e;
            xin[e * H + col] = (n < N) ? h[(size_t)n * H + col] : 0.f;
        }
    }
    __syncthreads();

    float a0[8], a1[8];
#pragma unroll
    for (int e = 0; e < 8; ++e) { a0[e] = 0.f; a1[e] = 0.f; }
    mlp_layer<32>(W1, xin, H, c0, eg * 8, a0, a1);
    {
        const float bb0 = b1[c0], bb1 = b1[c0 + 64];
#pragma unroll
        for (int e = 0; e < 8; ++e) {
            hm[(eg * 8 + e) * 132 + c0] = gelu_exact(a0[e] + bb0);
            hm[(eg * 8 + e) * 132 + c0 + 64] = gelu_exact(a1[e] + bb1);
        }
    }
    __syncthreads();
    {
        const int e = t >> 3;
        const int o = t & 7;
        const int n = n0 + e;
        float acc = b2[o];
#pragma unroll 4
        for (int k = 0; k < H; ++k)
            acc = fmaf(hm[e * 132 + k], W2[k * 8 + o], acc);
        if (n < N) out[n * 8 + o] = acc;
    }
}

extern "C" void kernel_launch(void* const* d_in, const int* in_sizes, int n_in,
                              void* d_out, int out_size, void* d_ws,
                              size_t ws_size, hipStream_t stream) {
    (void)n_in; (void)out_size; (void)ws_size;
    const float* nf      = (const float*)d_in[0];
    const int*   ei      = (const int*)d_in[1];
    const float* enc_W1  = (const float*)d_in[2];
    const float* enc_b1  = (const float*)d_in[3];
    const float* enc_W2  = (const float*)d_in[4];
    const float* enc_b2  = (const float*)d_in[5];
    const float* edge_W1 = (const float*)d_in[6];
    const float* edge_b1 = (const float*)d_in[7];
    const float* edge_W2 = (const float*)d_in[8];
    const float* edge_b2 = (const float*)d_in[9];
    const float* node_W1 = (const float*)d_in[10];
    const float* node_b1 = (const float*)d_in[11];
    const float* node_W2 = (const float*)d_in[12];
    const float* node_b2 = (const float*)d_in[13];
    const float* dec_W1  = (const float*)d_in[14];
    const float* dec_b1  = (const float*)d_in[15];
    const float* dec_W2  = (const float*)d_in[16];
    const float* dec_b2  = (const float*)d_in[17];

    const int N = in_sizes[0] / 16;
    const int E = in_sizes[1] / 2;
    const int L = in_sizes[7] / H;  // edge_b1 is [L,H]

    // ---------------- workspace layout ----------------
    char* ws = (char*)d_ws;
    float* h    = (float*)ws;                    ws += (size_t)N * H * 4;
    float* aggG = (float*)ws;                    ws += (size_t)N * H * 4;
    float* Bf32 = (float*)ws;                    ws += (size_t)N * H * 4;
    unsigned short* h_bf  = (unsigned short*)ws; ws += (size_t)N * H * 2;
    unsigned short* A_bf  = (unsigned short*)ws; ws += (size_t)N * H * 2;
    unsigned short* aggB  = (unsigned short*)ws; ws += (size_t)N * H * 2;
    int* srcS     = (int*)ws;                    ws += (size_t)E * 4;
    int* dstS     = (int*)ws;                    ws += (size_t)E * 4;
    int* deg      = (int*)ws;                    ws += (size_t)N * 4;
    int* rowStart = (int*)ws;                    ws += (size_t)N * 4;
    int* cursor   = (int*)ws;                    ws += (size_t)N * 4;
    unsigned short* eW1t = (unsigned short*)ws;  ws += (size_t)L * 2 * H * H * 2;
    unsigned short* eW2t = (unsigned short*)ws;  ws += (size_t)L * H * H * 2;
    unsigned short* nW1t = (unsigned short*)ws;  ws += (size_t)L * 2 * H * H * 2;
    unsigned short* nW2t = (unsigned short*)ws;  ws += (size_t)L * H * H * 2;

    const int* srcArr = ei;
    const int* dstArr = ei + E;

    // weight conversion (tiny)
    {
        const int t1 = L * 2 * H * H, t2 = L * H * H;
        wcvt_kernel<<<(t1 + NTHR - 1) / NTHR, NTHR, 0, stream>>>(edge_W1, eW1t, 2 * H, H, t1);
        wcvt_kernel<<<(t2 + NTHR - 1) / NTHR, NTHR, 0, stream>>>(edge_W2, eW2t, H, H, t2);
        wcvt_kernel<<<(t1 + NTHR - 1) / NTHR, NTHR, 0, stream>>>(node_W1, nW1t, 2 * H, H, t1);
        wcvt_kernel<<<(t2 + NTHR - 1) / NTHR, NTHR, 0, stream>>>(node_W2, nW2t, H, H, t2);
    }

    // sort edges by dst (hist + scan + scatter), once per launch
    hipMemsetAsync(deg, 0, (size_t)N * 4, stream);
    deg_kernel<<<(E + NTHR - 1) / NTHR, NTHR, 0, stream>>>(dstArr, deg, E);
    scan_kernel<<<1, 1024, 0, stream>>>(deg, rowStart, N);
    copy_kernel<<<(N + NTHR - 1) / NTHR, NTHR, 0, stream>>>(rowStart, cursor, N);
    scatter_kernel<<<(E + NTHR - 1) / NTHR, NTHR, 0, stream>>>(
        srcArr, dstArr, cursor, srcS, dstS, E);

    const int encBlocks  = (N + TILE - 1) / TILE;
    const int tileBlocks = (N + TE - 1) / TE;
    const int gatherBlks = (E + 4 * CHUNK - 1) / (4 * CHUNK);

    encode_kernel<<<encBlocks, NTHR, 0, stream>>>(nf, enc_W1, enc_b1, enc_W2,
                                                  enc_b2, h, h_bf, N);
    for (int l = 0; l < L; ++l) {
        ab_kernel<<<tileBlocks, NTHR, 0, stream>>>(
            h_bf, eW1t + (size_t)l * 2 * H * H, edge_b1 + (size_t)l * H, A_bf,
            Bf32, N);
        hipMemsetAsync(aggG, 0, (size_t)N * H * sizeof(float), stream);
        edge_gather_kernel<<<gatherBlks, NTHR, 0, stream>>>(A_bf, Bf32, srcS,
                                                            dstS, aggG, E);
        aggw2_kernel<<<tileBlocks, NTHR, 0, stream>>>(
            aggG, eW2t + (size_t)l * H * H, edge_b2 + (size_t)l * H, deg, aggB,
            N);
        node_mfma_kernel<<<tileBlocks, NTHR, 0, stream>>>(
            h, h_bf, aggB, nW1t + (size_t)l * 2 * H * H,
            node_b1 + (size_t)l * H, nW2t + (size_t)l * H * H,
            node_b2 + (size_t)l * H, N);
    }
    decode_kernel<<<encBlocks, NTHR, 0, stream>>>(h, dec_W1, dec_b1, dec_W2,
                                                  dec_b2, (float*)d_out, N);
}

// Round 4
// 901.691 us; speedup vs baseline: 6.5191x; 1.1283x over previous
//
#include <hip/hip_runtime.h>
#include <math.h>

// FieldlineGraphForecaster round 3:
//  - edge gather: node-range ownership per wave (chunkLo), plain stores,
//    branchless A&S erf (no atomics, no memset, no library erff).
//  - aggw2 folded into node MLP: Wcomb = eW2@nW1_bot (bf16), cvec = b2@nW1_bot,
//    node bias' = b1 + deg*cvec. aggG (fp32) feeds node GEMM directly.
//  - multi-block scan for rowStart.

constexpr int H = 128;
constexpr int NTHR = 256;
constexpr int TE = 64;    // rows per MFMA tile
constexpr int TILE = 32;  // rows per fp32 (enc/dec) tile

using bf16x8 = __attribute__((ext_vector_type(8))) short;
using f32x4  = __attribute__((ext_vector_type(4))) float;

__device__ __forceinline__ float gelu_exact(float x) {
    return 0.5f * x * (1.0f + erff(x * 0.70710678118654752440f));
}

// Branchless GELU: A&S 7.1.26 erf, |eps|<=1.5e-7. Self-clamping for |x| large
// (exp underflows to 0 -> erf=+-1).
__device__ __forceinline__ float gelu_fast(float x) {
    const float u = fabsf(x) * 0.70710678118654752440f;
    const float t = __builtin_amdgcn_rcpf(fmaf(0.3275911f, u, 1.f));
    float p = fmaf(1.061405429f, t, -1.453152027f);
    p = fmaf(p, t, 1.421413741f);
    p = fmaf(p, t, -0.284496736f);
    p = fmaf(p, t, 0.254829592f);
    p = p * t;
    const float e = __expf(-u * u);
    float er = fmaf(-p, e, 1.f);          // erf(|x|/sqrt2)
    er = copysignf(er, x);
    return 0.5f * x * (1.f + er);
}

__device__ __forceinline__ unsigned short f2bf(float f) {
    unsigned int u = __builtin_bit_cast(unsigned int, f);
    u = (u + 0x7fffu + ((u >> 16) & 1u)) >> 16;
    return (unsigned short)u;
}

__device__ __forceinline__ float bf2f_lo(unsigned int v) {
    return __builtin_bit_cast(float, v << 16);
}
__device__ __forceinline__ float bf2f_hi(unsigned int v) {
    return __builtin_bit_cast(float, v & 0xffff0000u);
}

// ---------- weight convert+transpose: W[l][K][N] -> Wt[l][N][K] bf16 ------
__global__ __launch_bounds__(NTHR) void wcvt_kernel(
    const float* __restrict__ W, unsigned short* __restrict__ Wt,
    int K, int Ncols, int total) {
    const int i = blockIdx.x * NTHR + threadIdx.x;
    if (i >= total) return;
    const int per = K * Ncols;
    const int l = i / per;
    const int r = i - l * per;
    const int n = r % Ncols;
    const int k = r / Ncols;
    Wt[(size_t)l * per + n * K + k] = f2bf(W[i]);
}

// ---- node_W1 top half: W[l][256][128] rows 0..127 -> Wt[l][128 col][256 k]
__global__ __launch_bounds__(NTHR) void wcvt_top_kernel(
    const float* __restrict__ W, unsigned short* __restrict__ Wt, int total) {
    const int i = blockIdx.x * NTHR + threadIdx.x;
    if (i >= total) return;
    const int per = H * H;  // top-half elements per layer
    const int l = i / per;
    const int r = i - l * per;
    const int k = r / H;    // 0..127
    const int o = r % H;
    Wt[(size_t)l * H * 2 * H + o * 2 * H + k] =
        f2bf(W[(size_t)l * 2 * H * H + k * H + o]);
}

// ---- Wcomb[j][o] = sum_c eW2[j][c]*nW1[128+c][o] -> Wt bottom half; and
//      cvec[o] = sum_c b2[c]*nW1[128+c][o] (j==128 block).
__global__ __launch_bounds__(H) void wcomb_kernel(
    const float* __restrict__ eW2, const float* __restrict__ eb2,
    const float* __restrict__ nW1, unsigned short* __restrict__ W1tc,
    float* __restrict__ cvec) {
    const int l = blockIdx.y;
    const int j = blockIdx.x;   // 0..128
    const int o = threadIdx.x;  // 0..127
    const float* w1 = nW1 + (size_t)l * 2 * H * H + (size_t)H * H;  // rows 128+
    const float* row = (j < H) ? (eW2 + (size_t)l * H * H + (size_t)j * H)
                               : (eb2 + (size_t)l * H);
    float s = 0.f;
#pragma unroll 4
    for (int c = 0; c < H; ++c) s = fmaf(row[c], w1[(size_t)c * H + o], s);
    if (j < H)
        W1tc[(size_t)l * H * 2 * H + o * 2 * H + H + j] = f2bf(s);
    else
        cvec[(size_t)l * H + o] = s;
}

// ----------------------- sort-by-dst machinery ----------------------------
__global__ __launch_bounds__(NTHR) void deg_kernel(const int* __restrict__ dst,
                                                   int* __restrict__ deg, int E) {
    const int e = blockIdx.x * NTHR + threadIdx.x;
    if (e < E) atomicAdd(&deg[dst[e]], 1);
}

__global__ __launch_bounds__(1024) void scan1_kernel(
    const int* __restrict__ deg, int* __restrict__ out,
    int* __restrict__ bsum, int N) {
    __shared__ int buf[1024];
    const int t = threadIdx.x;
    const int i = blockIdx.x * 1024 + t;
    const int x = (i < N) ? deg[i] : 0;
    buf[t] = x;
    __syncthreads();
    int v = x;
    for (int off = 1; off < 1024; off <<= 1) {
        const int y = (t >= off) ? buf[t - off] : 0;
        __syncthreads();
        v += y;
        buf[t] = v;
        __syncthreads();
    }
    if (i < N) out[i] = v - x;  // block-local exclusive
    if (t == 1023) bsum[blockIdx.x] = v;
}

__global__ void scan2_kernel(int* __restrict__ bsum, int nb) {
    if (threadIdx.x == 0) {
        int acc = 0;
        for (int i = 0; i < nb; ++i) {
            const int t = bsum[i];
            bsum[i] = acc;
            acc += t;
        }
    }
}

__global__ __launch_bounds__(NTHR) void scan3_kernel(
    int* __restrict__ out, const int* __restrict__ bsum, int N, int E) {
    const int i = blockIdx.x * NTHR + threadIdx.x;
    if (i < N) out[i] += bsum[i >> 10];
    else if (i == N) out[N] = E;
}

__global__ __launch_bounds__(NTHR) void copy_kernel(const int* __restrict__ a,
                                                    int* __restrict__ b, int n) {
    const int i = blockIdx.x * NTHR + threadIdx.x;
    if (i < n) b[i] = a[i];
}

// chunkLo[c] = min node n with rowStart[n]>>5 == c
__global__ __launch_bounds__(NTHR) void chunk_kernel(
    const int* __restrict__ rowStart, int* __restrict__ chunkLo, int N) {
    const int n = blockIdx.x * NTHR + threadIdx.x;
    if (n < N) atomicMin(&chunkLo[rowStart[n] >> 5], n);
}

__global__ __launch_bounds__(NTHR) void scatter_kernel(
    const int* __restrict__ src, const int* __restrict__ dst,
    int* __restrict__ cursor, int* __restrict__ srcS, int E) {
    const int e = blockIdx.x * NTHR + threadIdx.x;
    if (e >= E) return;
    const int pos = atomicAdd(&cursor[dst[e]], 1);
    srcS[pos] = src[e];
}

// ---- A/B kernel: A = h@W1_top (bf16), B = h@W1_bot + b1 (fp32) -----------
__global__ __launch_bounds__(NTHR) void ab_kernel(
    const unsigned short* __restrict__ h_bf,
    const unsigned short* __restrict__ W1t,  // [128 cols][256 k]
    const float* __restrict__ b1, unsigned short* __restrict__ A,
    float* __restrict__ Bout, int N) {
    __shared__ __align__(16) unsigned short X[TE * H];  // 16KB
    const int t = threadIdx.x;
    const int lane = t & 63;
    const int w = t >> 6;
    const int n0 = blockIdx.x * TE;
    const int l15 = lane & 15;
    const int lq = lane >> 4;

#pragma unroll
    for (int i = 0; i < 4; ++i) {
        const int c = i * NTHR + t;
        const int row = c >> 4;
        const int col8 = c & 15;
        const int n = n0 + row;
        const int4 v = (n < N)
            ? *reinterpret_cast<const int4*>(h_bf + (size_t)n * H + col8 * 8)
            : make_int4(0, 0, 0, 0);
        const int byteoff = row * 256 + ((col8 * 16) ^ ((row & 7) << 4));
        *reinterpret_cast<int4*>(reinterpret_cast<char*>(X) + byteoff) = v;
    }

    const int half = w >> 1;  // 0 -> A (k 0..127), 1 -> B (k 128..255)
    const int cbase = (w & 1) * 64;
    bf16x8 Bf[4][4];
#pragma unroll
    for (int cg = 0; cg < 4; ++cg) {
        const int col = cbase + cg * 16 + l15;
#pragma unroll
        for (int s = 0; s < 4; ++s)
            Bf[cg][s] = *reinterpret_cast<const bf16x8*>(
                W1t + (size_t)col * 256 + half * 128 + s * 32 + lq * 8);
    }
    __syncthreads();

    f32x4 acc[4][4];
#pragma unroll
    for (int rg = 0; rg < 4; ++rg)
#pragma unroll
        for (int cg = 0; cg < 4; ++cg) acc[rg][cg] = (f32x4)0.f;

#pragma unroll
    for (int s = 0; s < 4; ++s) {
        bf16x8 a[4];
#pragma unroll
        for (int rg = 0; rg < 4; ++rg) {
            const int row = rg * 16 + l15;
            const int byteoff = row * 256 + ((s * 64 + lq * 16) ^ ((row & 7) << 4));
            a[rg] = *reinterpret_cast<const bf16x8*>(
                reinterpret_cast<const char*>(X) + byteoff);
        }
#pragma unroll
        for (int rg = 0; rg < 4; ++rg)
#pragma unroll
            for (int cg = 0; cg < 4; ++cg)
                acc[rg][cg] = __builtin_amdgcn_mfma_f32_16x16x32_bf16(
                    a[rg], Bf[cg][s], acc[rg][cg], 0, 0, 0);
    }

#pragma unroll
    for (int cg = 0; cg < 4; ++cg) {
        const int col = cbase + cg * 16 + l15;
        const float bb = (half == 1) ? b1[col] : 0.f;
#pragma unroll
        for (int rg = 0; rg < 4; ++rg) {
#pragma unroll
            for (int r = 0; r < 4; ++r) {
                const int row = rg * 16 + lq * 4 + r;
                const int n = n0 + row;
                if (n < N) {
                    if (half == 0)
                        A[(size_t)n * H + col] = f2bf(acc[rg][cg][r]);
                    else
                        Bout[(size_t)n * H + col] = acc[rg][cg][r] + bb;
                }
            }
        }
    }
}

// ---- edge gather v2: wave owns node-range; plain stores, no atomics ------
__global__ __launch_bounds__(NTHR) void edge_gather_kernel(
    const unsigned short* __restrict__ A, const float* __restrict__ B,
    const int* __restrict__ srcS, const int* __restrict__ rowStart,  // N+1
    const int* __restrict__ chunkLo, float* __restrict__ aggG, int N, int E) {
    const int lane = threadIdx.x & 63;
    const int c = blockIdx.x * 4 + (threadIdx.x >> 6);
    const int nWaves = (E >> 5) + 1;
    if (c >= nWaves) return;
    int n = chunkLo[c];
    if (n >= N) return;  // sentinel: no node starts in this chunk
    const int Wend = (c + 1) * 32;
    const int c2 = lane * 2;
    while (n < N) {
        const int r0 = rowStart[n];
        if (r0 >= Wend) break;
        const int r1 = rowStart[n + 1];
        const float2 bv = *reinterpret_cast<const float2*>(B + (size_t)n * H + c2);
        float s0 = 0.f, s1 = 0.f;
        for (int e = r0; e < r1; ++e) {
            const int s = srcS[e];
            const unsigned int av =
                *reinterpret_cast<const unsigned int*>(A + (size_t)s * H + c2);
            s0 += gelu_fast(bf2f_lo(av) + bv.x);
            s1 += gelu_fast(bf2f_hi(av) + bv.y);
        }
        *reinterpret_cast<float2*>(aggG + (size_t)n * H + c2) =
            make_float2(s0, s1);
        ++n;
    }
}

// ---- node update: h += MLP([h | aggG] ; W1' = [nW1_top;Wcomb],
//      b1' = b1 + deg*cvec) ; refresh h_bf -----------------------------------
__global__ __launch_bounds__(NTHR) void node_mfma_kernel(
    float* __restrict__ h, unsigned short* __restrict__ h_bf,
    const float* __restrict__ aggG, const int* __restrict__ deg,
    const unsigned short* __restrict__ W1tc, const float* __restrict__ b1,
    const float* __restrict__ cvec, const unsigned short* __restrict__ W2t,
    const float* __restrict__ b2, int N) {
    __shared__ __align__(16) unsigned short X[TE * 256];
    __shared__ int degS[TE];
    const int t = threadIdx.x;
    const int lane = t & 63;
    const int w = t >> 6;
    const int n0 = blockIdx.x * TE;
    const int l15 = lane & 15;
    const int lq = lane >> 4;

    if (t < TE) degS[t] = (n0 + t < N) ? deg[n0 + t] : 0;
#pragma unroll
    for (int i = 0; i < 8; ++i) {
        const int c = i * NTHR + t;
        const int row = c >> 5;
        const int col8 = c & 31;
        const int n = n0 + row;
        int4 v = make_int4(0, 0, 0, 0);
        if (n < N) {
            if (col8 < 16) {
                v = *reinterpret_cast<const int4*>(h_bf + (size_t)n * H + col8 * 8);
            } else {
                const float* ap = aggG + (size_t)n * H + (col8 - 16) * 8;
                union { int4 q; unsigned short us[8]; } u;
#pragma unroll
                for (int j = 0; j < 8; ++j) u.us[j] = f2bf(ap[j]);
                v = u.q;
            }
        }
        const int byteoff = row * 512 + ((col8 * 16) ^ ((row & 7) << 4));
        *reinterpret_cast<int4*>(reinterpret_cast<char*>(X) + byteoff) = v;
    }

    bf16x8 B1[2][8];
#pragma unroll
    for (int cg = 0; cg < 2; ++cg) {
        const int col = w * 32 + cg * 16 + l15;
#pragma unroll
        for (int s = 0; s < 8; ++s)
            B1[cg][s] = *reinterpret_cast<const bf16x8*>(
                W1tc + (size_t)col * 256 + s * 32 + lq * 8);
    }
    __syncthreads();

    f32x4 acc[4][2];
#pragma unroll
    for (int rg = 0; rg < 4; ++rg)
#pragma unroll
        for (int cg = 0; cg < 2; ++cg) acc[rg][cg] = (f32x4)0.f;

#pragma unroll
    for (int s = 0; s < 8; ++s) {
        bf16x8 a[4];
#pragma unroll
        for (int rg = 0; rg < 4; ++rg) {
            const int row = rg * 16 + l15;
            const int byteoff = row * 512 + ((s * 64 + lq * 16) ^ ((row & 7) << 4));
            a[rg] = *reinterpret_cast<const bf16x8*>(
                reinterpret_cast<const char*>(X) + byteoff);
        }
#pragma unroll
        for (int rg = 0; rg < 4; ++rg)
#pragma unroll
            for (int cg = 0; cg < 2; ++cg)
                acc[rg][cg] = __builtin_amdgcn_mfma_f32_16x16x32_bf16(
                    a[rg], B1[cg][s], acc[rg][cg], 0, 0, 0);
    }
    __syncthreads();

#pragma unroll
    for (int cg = 0; cg < 2; ++cg) {
        const int col = w * 32 + cg * 16 + l15;
        const float bb = b1[col];
        const float cc = cvec[col];
#pragma unroll
        for (int rg = 0; rg < 4; ++rg) {
#pragma unroll
            for (int r = 0; r < 4; ++r) {
                const int row = rg * 16 + lq * 4 + r;
                const float v =
                    gelu_fast(acc[rg][cg][r] + bb + (float)degS[row] * cc);
                const int byteoff = row * 256 + ((col * 2) ^ ((row & 7) << 4));
                *reinterpret_cast<unsigned short*>(
                    reinterpret_cast<char*>(X) + byteoff) = f2bf(v);
            }
        }
    }

    bf16x8 B2[2][4];
#pragma unroll
    for (int cg = 0; cg < 2; ++cg) {
        const int col = w * 32 + cg * 16 + l15;
#pragma unroll
        for (int s = 0; s < 4; ++s)
            B2[cg][s] = *reinterpret_cast<const bf16x8*>(
                W2t + (size_t)col * 128 + s * 32 + lq * 8);
    }
    __syncthreads();

    f32x4 acc2[4][2];
#pragma unroll
    for (int rg = 0; rg < 4; ++rg)
#pragma unroll
        for (int cg = 0; cg < 2; ++cg) acc2[rg][cg] = (f32x4)0.f;

#pragma unroll
    for (int s = 0; s < 4; ++s) {
        bf16x8 a[4];
#pragma unroll
        for (int rg = 0; rg < 4; ++rg) {
            const int row = rg * 16 + l15;
            const int byteoff = row * 256 + ((s * 64 + lq * 16) ^ ((row & 7) << 4));
            a[rg] = *reinterpret_cast<const bf16x8*>(
                reinterpret_cast<const char*>(X) + byteoff);
        }
#pragma unroll
        for (int rg = 0; rg < 4; ++rg)
#pragma unroll
            for (int cg = 0; cg < 2; ++cg)
                acc2[rg][cg] = __builtin_amdgcn_mfma_f32_16x16x32_bf16(
                    a[rg], B2[cg][s], acc2[rg][cg], 0, 0, 0);
    }

#pragma unroll
    for (int cg = 0; cg < 2; ++cg) {
        const int col = w * 32 + cg * 16 + l15;
        const float bb = b2[col];
#pragma unroll
        for (int rg = 0; rg < 4; ++rg) {
#pragma unroll
            for (int r = 0; r < 4; ++r) {
                const int row = rg * 16 + lq * 4 + r;
                const int n = n0 + row;
                if (n < N) {
                    const float hv = h[(size_t)n * H + col] + acc2[rg][cg][r] + bb;
                    h[(size_t)n * H + col] = hv;
                    h_bf[(size_t)n * H + col] = f2bf(hv);
                }
            }
        }
    }
}

// ---------------- fp32 helper for encoder/decoder -------------------------
template <int K4>
__device__ __forceinline__ void mlp_layer(const float* __restrict__ W,
                                          const float* lds, int ldsStride,
                                          int c0, int egBase,
                                          float a0[8], float a1[8]) {
#pragma unroll 2
    for (int k4 = 0; k4 < K4; ++k4) {
        const float w00 = W[(k4 * 4 + 0) * H + c0];
        const float w01 = W[(k4 * 4 + 1) * H + c0];
        const float w02 = W[(k4 * 4 + 2) * H + c0];
        const float w03 = W[(k4 * 4 + 3) * H + c0];
        const float w10 = W[(k4 * 4 + 0) * H + c0 + 64];
        const float w11 = W[(k4 * 4 + 1) * H + c0 + 64];
        const float w12 = W[(k4 * 4 + 2) * H + c0 + 64];
        const float w13 = W[(k4 * 4 + 3) * H + c0 + 64];
#pragma unroll
        for (int e = 0; e < 8; ++e) {
            const float4 x = *reinterpret_cast<const float4*>(
                &lds[(egBase + e) * ldsStride + k4 * 4]);
            a0[e] = fmaf(x.x, w00, a0[e]);
            a0[e] = fmaf(x.y, w01, a0[e]);
            a0[e] = fmaf(x.z, w02, a0[e]);
            a0[e] = fmaf(x.w, w03, a0[e]);
            a1[e] = fmaf(x.x, w10, a1[e]);
            a1[e] = fmaf(x.y, w11, a1[e]);
            a1[e] = fmaf(x.z, w12, a1[e]);
            a1[e] = fmaf(x.w, w13, a1[e]);
        }
    }
}

// ---------------- encoder: [N,16] -> MLP -> h fp32 + h_bf bf16 ------------
__global__ __launch_bounds__(NTHR) void encode_kernel(
    const float* __restrict__ nf, const float* __restrict__ W1,
    const float* __restrict__ b1, const float* __restrict__ W2,
    const float* __restrict__ b2, float* __restrict__ h,
    unsigned short* __restrict__ h_bf, int N) {
    __shared__ float xin[TILE * 16];
    __shared__ float hm[TILE * H];
    const int t = threadIdx.x;
    const int n0 = blockIdx.x * TILE;
    const int c0 = t & 63;
    const int eg = t >> 6;

    for (int i = t; i < TILE * 16; i += NTHR) {
        const int gi = n0 * 16 + i;
        xin[i] = (gi < N * 16) ? nf[gi] : 0.f;
    }
    __syncthreads();

    float a0[8], a1[8];
#pragma unroll
    for (int e = 0; e < 8; ++e) { a0[e] = 0.f; a1[e] = 0.f; }
    mlp_layer<4>(W1, xin, 16, c0, eg * 8, a0, a1);
    {
        const float bb0 = b1[c0], bb1 = b1[c0 + 64];
#pragma unroll
        for (int e = 0; e < 8; ++e) {
            hm[(eg * 8 + e) * H + c0] = gelu_fast(a0[e] + bb0);
            hm[(eg * 8 + e) * H + c0 + 64] = gelu_fast(a1[e] + bb1);
        }
    }
    __syncthreads();
#pragma unroll
    for (int e = 0; e < 8; ++e) { a0[e] = 0.f; a1[e] = 0.f; }
    mlp_layer<32>(W2, hm, H, c0, eg * 8, a0, a1);
    const float bb0 = b2[c0], bb1 = b2[c0 + 64];
#pragma unroll
    for (int e = 0; e < 8; ++e) {
        const int n = n0 + eg * 8 + e;
        if (n < N) {
            const float v0 = a0[e] + bb0, v1 = a1[e] + bb1;
            h[(size_t)n * H + c0] = v0;
            h[(size_t)n * H + c0 + 64] = v1;
            h_bf[(size_t)n * H + c0] = f2bf(v0);
            h_bf[(size_t)n * H + c0 + 64] = f2bf(v1);
        }
    }
}

// --------------- decoder: h -> GELU MLP -> out [N,8] ----------------------
__global__ __launch_bounds__(NTHR) void decode_kernel(
    const float* __restrict__ h, const float* __restrict__ W1,
    const float* __restrict__ b1, const float* __restrict__ W2,
    const float* __restrict__ b2, float* __restrict__ out, int N) {
    __shared__ float xin[TILE * H];
    __shared__ float hm[TILE * 132];
    const int t = threadIdx.x;
    const int n0 = blockIdx.x * TILE;
    const int c0 = t & 63;
    const int eg = t >> 6;
    {
        const int col = t & 127;
        for (int e = t >> 7; e < TILE; e += 2) {
            const int n = n0 + e;
            xin[e * H + col] = (n < N) ? h[(size_t)n * H + col] : 0.f;
        }
    }
    __syncthreads();

    float a0[8], a1[8];
#pragma unroll
    for (int e = 0; e < 8; ++e) { a0[e] = 0.f; a1[e] = 0.f; }
    mlp_layer<32>(W1, xin, H, c0, eg * 8, a0, a1);
    {
        const float bb0 = b1[c0], bb1 = b1[c0 + 64];
#pragma unroll
        for (int e = 0; e < 8; ++e) {
            hm[(eg * 8 + e) * 132 + c0] = gelu_fast(a0[e] + bb0);
            hm[(eg * 8 + e) * 132 + c0 + 64] = gelu_fast(a1[e] + bb1);
        }
    }
    __syncthreads();
    {
        const int e = t >> 3;
        const int o = t & 7;
        const int n = n0 + e;
        float acc = b2[o];
#pragma unroll 4
        for (int k = 0; k < H; ++k)
            acc = fmaf(hm[e * 132 + k], W2[k * 8 + o], acc);
        if (n < N) out[n * 8 + o] = acc;
    }
}

extern "C" void kernel_launch(void* const* d_in, const int* in_sizes, int n_in,
                              void* d_out, int out_size, void* d_ws,
                              size_t ws_size, hipStream_t stream) {
    (void)n_in; (void)out_size; (void)ws_size;
    const float* nf      = (const float*)d_in[0];
    const int*   ei      = (const int*)d_in[1];
    const float* enc_W1  = (const float*)d_in[2];
    const float* enc_b1  = (const float*)d_in[3];
    const float* enc_W2  = (const float*)d_in[4];
    const float* enc_b2  = (const float*)d_in[5];
    const float* edge_W1 = (const float*)d_in[6];
    const float* edge_b1 = (const float*)d_in[7];
    const float* edge_W2 = (const float*)d_in[8];
    const float* edge_b2 = (const float*)d_in[9];
    const float* node_W1 = (const float*)d_in[10];
    const float* node_b1 = (const float*)d_in[11];
    const float* node_W2 = (const float*)d_in[12];
    const float* node_b2 = (const float*)d_in[13];
    const float* dec_W1  = (const float*)d_in[14];
    const float* dec_b1  = (const float*)d_in[15];
    const float* dec_W2  = (const float*)d_in[16];
    const float* dec_b2  = (const float*)d_in[17];

    const int N = in_sizes[0] / 16;
    const int E = in_sizes[1] / 2;
    const int L = in_sizes[7] / H;  // edge_b1 is [L,H]
    const int numChunks = (E >> 5) + 1;

    // ---------------- workspace layout ----------------
    char* ws = (char*)d_ws;
    float* h    = (float*)ws;                    ws += (size_t)N * H * 4;
    float* aggG = (float*)ws;                    ws += (size_t)N * H * 4;
    float* Bf32 = (float*)ws;                    ws += (size_t)N * H * 4;
    unsigned short* h_bf  = (unsigned short*)ws; ws += (size_t)N * H * 2;
    unsigned short* A_bf  = (unsigned short*)ws; ws += (size_t)N * H * 2;
    int* srcS     = (int*)ws;                    ws += (size_t)E * 4;
    int* deg      = (int*)ws;                    ws += (size_t)N * 4;
    int* rowStart = (int*)ws;                    ws += (size_t)(N + 1) * 4;
    int* cursor   = (int*)ws;                    ws += (size_t)N * 4;
    int* bsum     = (int*)ws;                    ws += (size_t)256 * 4;
    int* chunkLo  = (int*)ws;                    ws += (size_t)numChunks * 4;
    unsigned short* eW1t = (unsigned short*)ws;  ws += (size_t)L * 2 * H * H * 2;
    unsigned short* nW1tc = (unsigned short*)ws; ws += (size_t)L * 2 * H * H * 2;
    unsigned short* nW2t = (unsigned short*)ws;  ws += (size_t)L * H * H * 2;
    float* cvec   = (float*)ws;                  ws += (size_t)L * H * 4;

    const int* srcArr = ei;
    const int* dstArr = ei + E;

    // ---- weight prep (tiny) ----
    {
        const int t1 = L * 2 * H * H, t2 = L * H * H;
        wcvt_kernel<<<(t1 + NTHR - 1) / NTHR, NTHR, 0, stream>>>(edge_W1, eW1t, 2 * H, H, t1);
        wcvt_kernel<<<(t2 + NTHR - 1) / NTHR, NTHR, 0, stream>>>(node_W2, nW2t, H, H, t2);
        wcvt_top_kernel<<<(t2 + NTHR - 1) / NTHR, NTHR, 0, stream>>>(node_W1, nW1tc, t2);
        wcomb_kernel<<<dim3(H + 1, L), H, 0, stream>>>(edge_W2, edge_b2,
                                                       node_W1, nW1tc, cvec);
    }

    // ---- sort edges by dst (hist + multiblock scan + scatter) ----
    hipMemsetAsync(deg, 0, (size_t)N * 4, stream);
    deg_kernel<<<(E + NTHR - 1) / NTHR, NTHR, 0, stream>>>(dstArr, deg, E);
    const int nScanB = (N + 1023) / 1024;
    scan1_kernel<<<nScanB, 1024, 0, stream>>>(deg, rowStart, bsum, N);
    scan2_kernel<<<1, 64, 0, stream>>>(bsum, nScanB);
    scan3_kernel<<<(N + 1 + NTHR - 1) / NTHR, NTHR, 0, stream>>>(rowStart, bsum,
                                                                 N, E);
    hipMemsetAsync(chunkLo, 0x7f, (size_t)numChunks * 4, stream);
    chunk_kernel<<<(N + NTHR - 1) / NTHR, NTHR, 0, stream>>>(rowStart, chunkLo, N);
    copy_kernel<<<(N + NTHR - 1) / NTHR, NTHR, 0, stream>>>(rowStart, cursor, N);
    scatter_kernel<<<(E + NTHR - 1) / NTHR, NTHR, 0, stream>>>(srcArr, dstArr,
                                                               cursor, srcS, E);

    const int encBlocks  = (N + TILE - 1) / TILE;
    const int tileBlocks = (N + TE - 1) / TE;
    const int gatherBlks = (numChunks + 3) / 4;

    encode_kernel<<<encBlocks, NTHR, 0, stream>>>(nf, enc_W1, enc_b1, enc_W2,
                                                  enc_b2, h, h_bf, N);
    for (int l = 0; l < L; ++l) {
        ab_kernel<<<tileBlocks, NTHR, 0, stream>>>(
            h_bf, eW1t + (size_t)l * 2 * H * H, edge_b1 + (size_t)l * H, A_bf,
            Bf32, N);
        edge_gather_kernel<<<gatherBlks, NTHR, 0, stream>>>(
            A_bf, Bf32, srcS, rowStart, chunkLo, aggG, N, E);
        node_mfma_kernel<<<tileBlocks, NTHR, 0, stream>>>(
            h, h_bf, aggG, deg, nW1tc + (size_t)l * 2 * H * H,
            node_b1 + (size_t)l * H, cvec + (size_t)l * H,
            nW2t + (size_t)l * H * H, node_b2 + (size_t)l * H, N);
    }
    decode_kernel<<<encBlocks, NTHR, 0, stream>>>(h, dec_W1, dec_b1, dec_W2,
                                                  dec_b2, (float*)d_out, N);
}

// Round 5
// 718.965 us; speedup vs baseline: 8.1760x; 1.2542x over previous
//
#include <hip/hip_runtime.h>
#include <math.h>

// FieldlineGraphForecaster round 4:
//  - edge gather: 4x manual edge unroll (4 srcS + 4 A-row loads in flight)
//    to hide the serial load-load-VALU dependent chain (latency-bound at r3).
//  - ab_kernel fused into node kernel epilogue (layers 1..L-1): h_new tile in
//    LDS feeds two extra 64x128x128 MFMA passes producing next layer's A/B.
//  - copy_kernel folded into scan3.

constexpr int H = 128;
constexpr int NTHR = 256;
constexpr int TE = 64;    // rows per MFMA tile
constexpr int TILE = 32;  // rows per fp32 (enc/dec) tile

using bf16x8 = __attribute__((ext_vector_type(8))) short;
using f32x4  = __attribute__((ext_vector_type(4))) float;

// Branchless GELU: A&S 7.1.26 erf, |eps|<=1.5e-7.
__device__ __forceinline__ float gelu_fast(float x) {
    const float u = fabsf(x) * 0.70710678118654752440f;
    const float t = __builtin_amdgcn_rcpf(fmaf(0.3275911f, u, 1.f));
    float p = fmaf(1.061405429f, t, -1.453152027f);
    p = fmaf(p, t, 1.421413741f);
    p = fmaf(p, t, -0.284496736f);
    p = fmaf(p, t, 0.254829592f);
    p = p * t;
    const float e = __expf(-u * u);
    float er = fmaf(-p, e, 1.f);  // erf(|x|/sqrt2)
    er = copysignf(er, x);
    return 0.5f * x * (1.f + er);
}

__device__ __forceinline__ unsigned short f2bf(float f) {
    unsigned int u = __builtin_bit_cast(unsigned int, f);
    u = (u + 0x7fffu + ((u >> 16) & 1u)) >> 16;
    return (unsigned short)u;
}

__device__ __forceinline__ float bf2f_lo(unsigned int v) {
    return __builtin_bit_cast(float, v << 16);
}
__device__ __forceinline__ float bf2f_hi(unsigned int v) {
    return __builtin_bit_cast(float, v & 0xffff0000u);
}

// ---------- weight convert+transpose: W[l][K][N] -> Wt[l][N][K] bf16 ------
__global__ __launch_bounds__(NTHR) void wcvt_kernel(
    const float* __restrict__ W, unsigned short* __restrict__ Wt,
    int K, int Ncols, int total) {
    const int i = blockIdx.x * NTHR + threadIdx.x;
    if (i >= total) return;
    const int per = K * Ncols;
    const int l = i / per;
    const int r = i - l * per;
    const int n = r % Ncols;
    const int k = r / Ncols;
    Wt[(size_t)l * per + n * K + k] = f2bf(W[i]);
}

// ---- node_W1 top half: W[l][256][128] rows 0..127 -> Wt[l][128 col][256 k]
__global__ __launch_bounds__(NTHR) void wcvt_top_kernel(
    const float* __restrict__ W, unsigned short* __restrict__ Wt, int total) {
    const int i = blockIdx.x * NTHR + threadIdx.x;
    if (i >= total) return;
    const int per = H * H;
    const int l = i / per;
    const int r = i - l * per;
    const int k = r / H;
    const int o = r % H;
    Wt[(size_t)l * H * 2 * H + o * 2 * H + k] =
        f2bf(W[(size_t)l * 2 * H * H + k * H + o]);
}

// ---- Wcomb[j][o] = sum_c eW2[j][c]*nW1[128+c][o] -> Wt bottom half; and
//      cvec[o] = sum_c b2[c]*nW1[128+c][o] (j==128 block).
__global__ __launch_bounds__(H) void wcomb_kernel(
    const float* __restrict__ eW2, const float* __restrict__ eb2,
    const float* __restrict__ nW1, unsigned short* __restrict__ W1tc,
    float* __restrict__ cvec) {
    const int l = blockIdx.y;
    const int j = blockIdx.x;   // 0..128
    const int o = threadIdx.x;  // 0..127
    const float* w1 = nW1 + (size_t)l * 2 * H * H + (size_t)H * H;
    const float* row = (j < H) ? (eW2 + (size_t)l * H * H + (size_t)j * H)
                               : (eb2 + (size_t)l * H);
    float s = 0.f;
#pragma unroll 4
    for (int c = 0; c < H; ++c) s = fmaf(row[c], w1[(size_t)c * H + o], s);
    if (j < H)
        W1tc[(size_t)l * H * 2 * H + o * 2 * H + H + j] = f2bf(s);
    else
        cvec[(size_t)l * H + o] = s;
}

// ----------------------- sort-by-dst machinery ----------------------------
__global__ __launch_bounds__(NTHR) void deg_kernel(const int* __restrict__ dst,
                                                   int* __restrict__ deg, int E) {
    const int e = blockIdx.x * NTHR + threadIdx.x;
    if (e < E) atomicAdd(&deg[dst[e]], 1);
}

__global__ __launch_bounds__(1024) void scan1_kernel(
    const int* __restrict__ deg, int* __restrict__ out,
    int* __restrict__ bsum, int N) {
    __shared__ int buf[1024];
    const int t = threadIdx.x;
    const int i = blockIdx.x * 1024 + t;
    const int x = (i < N) ? deg[i] : 0;
    buf[t] = x;
    __syncthreads();
    int v = x;
    for (int off = 1; off < 1024; off <<= 1) {
        const int y = (t >= off) ? buf[t - off] : 0;
        __syncthreads();
        v += y;
        buf[t] = v;
        __syncthreads();
    }
    if (i < N) out[i] = v - x;  // block-local exclusive
    if (t == 1023) bsum[blockIdx.x] = v;
}

__global__ void scan2_kernel(int* __restrict__ bsum, int nb) {
    if (threadIdx.x == 0) {
        int acc = 0;
        for (int i = 0; i < nb; ++i) {
            const int t = bsum[i];
            bsum[i] = acc;
            acc += t;
        }
    }
}

__global__ __launch_bounds__(NTHR) void scan3_kernel(
    int* __restrict__ out, int* __restrict__ cursor,
    const int* __restrict__ bsum, int N, int E) {
    const int i = blockIdx.x * NTHR + threadIdx.x;
    if (i < N) {
        const int v = out[i] + bsum[i >> 10];
        out[i] = v;
        cursor[i] = v;
    } else if (i == N) {
        out[N] = E;
    }
}

// chunkLo[c] = min node n with rowStart[n]>>5 == c
__global__ __launch_bounds__(NTHR) void chunk_kernel(
    const int* __restrict__ rowStart, int* __restrict__ chunkLo, int N) {
    const int n = blockIdx.x * NTHR + threadIdx.x;
    if (n < N) atomicMin(&chunkLo[rowStart[n] >> 5], n);
}

__global__ __launch_bounds__(NTHR) void scatter_kernel(
    const int* __restrict__ src, const int* __restrict__ dst,
    int* __restrict__ cursor, int* __restrict__ srcS, int E) {
    const int e = blockIdx.x * NTHR + threadIdx.x;
    if (e >= E) return;
    const int pos = atomicAdd(&cursor[dst[e]], 1);
    srcS[pos] = src[e];
}

// ---- A/B kernel (layer 0 only): A = h@W1_top (bf16), B = h@W1_bot+b1 -----
__global__ __launch_bounds__(NTHR) void ab_kernel(
    const unsigned short* __restrict__ h_bf,
    const unsigned short* __restrict__ W1t,  // [128 cols][256 k]
    const float* __restrict__ b1, unsigned short* __restrict__ A,
    float* __restrict__ Bout, int N) {
    __shared__ __align__(16) unsigned short X[TE * H];  // 16KB
    const int t = threadIdx.x;
    const int lane = t & 63;
    const int w = t >> 6;
    const int n0 = blockIdx.x * TE;
    const int l15 = lane & 15;
    const int lq = lane >> 4;

#pragma unroll
    for (int i = 0; i < 4; ++i) {
        const int c = i * NTHR + t;
        const int row = c >> 4;
        const int col8 = c & 15;
        const int n = n0 + row;
        const int4 v = (n < N)
            ? *reinterpret_cast<const int4*>(h_bf + (size_t)n * H + col8 * 8)
            : make_int4(0, 0, 0, 0);
        const int byteoff = row * 256 + ((col8 * 16) ^ ((row & 7) << 4));
        *reinterpret_cast<int4*>(reinterpret_cast<char*>(X) + byteoff) = v;
    }

    const int half = w >> 1;  // 0 -> A, 1 -> B
    const int cbase = (w & 1) * 64;
    bf16x8 Bf[4][4];
#pragma unroll
    for (int cg = 0; cg < 4; ++cg) {
        const int col = cbase + cg * 16 + l15;
#pragma unroll
        for (int s = 0; s < 4; ++s)
            Bf[cg][s] = *reinterpret_cast<const bf16x8*>(
                W1t + (size_t)col * 256 + half * 128 + s * 32 + lq * 8);
    }
    __syncthreads();

    f32x4 acc[4][4];
#pragma unroll
    for (int rg = 0; rg < 4; ++rg)
#pragma unroll
        for (int cg = 0; cg < 4; ++cg) acc[rg][cg] = (f32x4)0.f;

#pragma unroll
    for (int s = 0; s < 4; ++s) {
        bf16x8 a[4];
#pragma unroll
        for (int rg = 0; rg < 4; ++rg) {
            const int row = rg * 16 + l15;
            const int byteoff = row * 256 + ((s * 64 + lq * 16) ^ ((row & 7) << 4));
            a[rg] = *reinterpret_cast<const bf16x8*>(
                reinterpret_cast<const char*>(X) + byteoff);
        }
#pragma unroll
        for (int rg = 0; rg < 4; ++rg)
#pragma unroll
            for (int cg = 0; cg < 4; ++cg)
                acc[rg][cg] = __builtin_amdgcn_mfma_f32_16x16x32_bf16(
                    a[rg], Bf[cg][s], acc[rg][cg], 0, 0, 0);
    }

#pragma unroll
    for (int cg = 0; cg < 4; ++cg) {
        const int col = cbase + cg * 16 + l15;
        const float bb = (half == 1) ? b1[col] : 0.f;
#pragma unroll
        for (int rg = 0; rg < 4; ++rg) {
#pragma unroll
            for (int r = 0; r < 4; ++r) {
                const int row = rg * 16 + lq * 4 + r;
                const int n = n0 + row;
                if (n < N) {
                    if (half == 0)
                        A[(size_t)n * H + col] = f2bf(acc[rg][cg][r]);
                    else
                        Bout[(size_t)n * H + col] = acc[rg][cg][r] + bb;
                }
            }
        }
    }
}

// ---- edge gather v3: node-range ownership + 4x edge unroll ---------------
__global__ __launch_bounds__(NTHR) void edge_gather_kernel(
    const unsigned short* __restrict__ A, const float* __restrict__ B,
    const int* __restrict__ srcS, const int* __restrict__ rowStart,  // N+1
    const int* __restrict__ chunkLo, float* __restrict__ aggG, int N, int E) {
    const int lane = threadIdx.x & 63;
    const int c = blockIdx.x * 4 + (threadIdx.x >> 6);
    const int nWaves = (E >> 5) + 1;
    if (c >= nWaves) return;
    int n = chunkLo[c];
    if (n >= N) return;  // sentinel: no node starts in this chunk
    const int Wend = (c + 1) * 32;
    const int c2 = lane * 2;
    int r0 = rowStart[n];
    while (true) {
        const int r1 = rowStart[n + 1];
        const float2 bv = *reinterpret_cast<const float2*>(B + (size_t)n * H + c2);
        float s0 = 0.f, s1 = 0.f;
        int e = r0;
        for (; e + 4 <= r1; e += 4) {
            const int sa = srcS[e];
            const int sb = srcS[e + 1];
            const int sc = srcS[e + 2];
            const int sd = srcS[e + 3];
            const unsigned int va =
                *reinterpret_cast<const unsigned int*>(A + (size_t)sa * H + c2);
            const unsigned int vb =
                *reinterpret_cast<const unsigned int*>(A + (size_t)sb * H + c2);
            const unsigned int vc =
                *reinterpret_cast<const unsigned int*>(A + (size_t)sc * H + c2);
            const unsigned int vd =
                *reinterpret_cast<const unsigned int*>(A + (size_t)sd * H + c2);
            s0 += gelu_fast(bf2f_lo(va) + bv.x);
            s1 += gelu_fast(bf2f_hi(va) + bv.y);
            s0 += gelu_fast(bf2f_lo(vb) + bv.x);
            s1 += gelu_fast(bf2f_hi(vb) + bv.y);
            s0 += gelu_fast(bf2f_lo(vc) + bv.x);
            s1 += gelu_fast(bf2f_hi(vc) + bv.y);
            s0 += gelu_fast(bf2f_lo(vd) + bv.x);
            s1 += gelu_fast(bf2f_hi(vd) + bv.y);
        }
        for (; e < r1; ++e) {
            const int s = srcS[e];
            const unsigned int av =
                *reinterpret_cast<const unsigned int*>(A + (size_t)s * H + c2);
            s0 += gelu_fast(bf2f_lo(av) + bv.x);
            s1 += gelu_fast(bf2f_hi(av) + bv.y);
        }
        *reinterpret_cast<float2*>(aggG + (size_t)n * H + c2) =
            make_float2(s0, s1);
        if (++n >= N) break;
        r0 = r1;
        if (r0 >= Wend) break;
    }
}

// ---- fused node update (+ next-layer A/B production) ---------------------
// h += MLP([h | aggG]; W1'=[nW1_top;Wcomb], b1'=b1+deg*cvec); refresh h_bf.
// If PROD: A_out = h_new@eW1_top(next), B_out = h_new@eW1_bot(next)+eb1(next).
template <bool PROD>
__global__ __launch_bounds__(NTHR) void node_fused_kernel(
    float* __restrict__ h, unsigned short* __restrict__ h_bf,
    const float* __restrict__ aggG, const int* __restrict__ deg,
    const unsigned short* __restrict__ W1tc, const float* __restrict__ b1,
    const float* __restrict__ cvec, const unsigned short* __restrict__ W2t,
    const float* __restrict__ b2, const unsigned short* __restrict__ eW1tN,
    const float* __restrict__ eb1N, unsigned short* __restrict__ A_out,
    float* __restrict__ B_out, int N) {
    __shared__ __align__(16) unsigned short X[TE * 256];  // 32KB
    __shared__ int degS[TE];
    const int t = threadIdx.x;
    const int lane = t & 63;
    const int w = t >> 6;
    const int n0 = blockIdx.x * TE;
    const int l15 = lane & 15;
    const int lq = lane >> 4;

    if (t < TE) degS[t] = (n0 + t < N) ? deg[n0 + t] : 0;
#pragma unroll
    for (int i = 0; i < 8; ++i) {
        const int c = i * NTHR + t;
        const int row = c >> 5;
        const int col8 = c & 31;
        const int n = n0 + row;
        int4 v = make_int4(0, 0, 0, 0);
        if (n < N) {
            if (col8 < 16) {
                v = *reinterpret_cast<const int4*>(h_bf + (size_t)n * H + col8 * 8);
            } else {
                const float* ap = aggG + (size_t)n * H + (col8 - 16) * 8;
                union { int4 q; unsigned short us[8]; } u;
#pragma unroll
                for (int j = 0; j < 8; ++j) u.us[j] = f2bf(ap[j]);
                v = u.q;
            }
        }
        const int byteoff = row * 512 + ((col8 * 16) ^ ((row & 7) << 4));
        *reinterpret_cast<int4*>(reinterpret_cast<char*>(X) + byteoff) = v;
    }

    bf16x8 B1[2][8];
#pragma unroll
    for (int cg = 0; cg < 2; ++cg) {
        const int col = w * 32 + cg * 16 + l15;
#pragma unroll
        for (int s = 0; s < 8; ++s)
            B1[cg][s] = *reinterpret_cast<const bf16x8*>(
                W1tc + (size_t)col * 256 + s * 32 + lq * 8);
    }
    __syncthreads();

    f32x4 acc[4][2];
#pragma unroll
    for (int rg = 0; rg < 4; ++rg)
#pragma unroll
        for (int cg = 0; cg < 2; ++cg) acc[rg][cg] = (f32x4)0.f;

#pragma unroll
    for (int s = 0; s < 8; ++s) {
        bf16x8 a[4];
#pragma unroll
        for (int rg = 0; rg < 4; ++rg) {
            const int row = rg * 16 + l15;
            const int byteoff = row * 512 + ((s * 64 + lq * 16) ^ ((row & 7) << 4));
            a[rg] = *reinterpret_cast<const bf16x8*>(
                reinterpret_cast<const char*>(X) + byteoff);
        }
#pragma unroll
        for (int rg = 0; rg < 4; ++rg)
#pragma unroll
            for (int cg = 0; cg < 2; ++cg)
                acc[rg][cg] = __builtin_amdgcn_mfma_f32_16x16x32_bf16(
                    a[rg], B1[cg][s], acc[rg][cg], 0, 0, 0);
    }
    __syncthreads();

    // L1 epilogue: gelu(acc + b1 + deg*cvec) -> hm (LDS bytes 0..16K)
#pragma unroll
    for (int cg = 0; cg < 2; ++cg) {
        const int col = w * 32 + cg * 16 + l15;
        const float bb = b1[col];
        const float cc = cvec[col];
#pragma unroll
        for (int rg = 0; rg < 4; ++rg) {
#pragma unroll
            for (int r = 0; r < 4; ++r) {
                const int row = rg * 16 + lq * 4 + r;
                const float v =
                    gelu_fast(acc[rg][cg][r] + bb + (float)degS[row] * cc);
                const int byteoff = row * 256 + ((col * 2) ^ ((row & 7) << 4));
                *reinterpret_cast<unsigned short*>(
                    reinterpret_cast<char*>(X) + byteoff) = f2bf(v);
            }
        }
    }

    bf16x8 B2[2][4];
#pragma unroll
    for (int cg = 0; cg < 2; ++cg) {
        const int col = w * 32 + cg * 16 + l15;
#pragma unroll
        for (int s = 0; s < 4; ++s)
            B2[cg][s] = *reinterpret_cast<const bf16x8*>(
                W2t + (size_t)col * 128 + s * 32 + lq * 8);
    }
    __syncthreads();

    f32x4 acc2[4][2];
#pragma unroll
    for (int rg = 0; rg < 4; ++rg)
#pragma unroll
        for (int cg = 0; cg < 2; ++cg) acc2[rg][cg] = (f32x4)0.f;

#pragma unroll
    for (int s = 0; s < 4; ++s) {
        bf16x8 a[4];
#pragma unroll
        for (int rg = 0; rg < 4; ++rg) {
            const int row = rg * 16 + l15;
            const int byteoff = row * 256 + ((s * 64 + lq * 16) ^ ((row & 7) << 4));
            a[rg] = *reinterpret_cast<const bf16x8*>(
                reinterpret_cast<const char*>(X) + byteoff);
        }
#pragma unroll
        for (int rg = 0; rg < 4; ++rg)
#pragma unroll
            for (int cg = 0; cg < 2; ++cg)
                acc2[rg][cg] = __builtin_amdgcn_mfma_f32_16x16x32_bf16(
                    a[rg], B2[cg][s], acc2[rg][cg], 0, 0, 0);
    }

    // residual write: h += update; refresh h_bf; h_new bf16 -> LDS @16KB
#pragma unroll
    for (int cg = 0; cg < 2; ++cg) {
        const int col = w * 32 + cg * 16 + l15;
        const float bb = b2[col];
#pragma unroll
        for (int rg = 0; rg < 4; ++rg) {
#pragma unroll
            for (int r = 0; r < 4; ++r) {
                const int row = rg * 16 + lq * 4 + r;
                const int n = n0 + row;
                if (n < N) {
                    const float hv = h[(size_t)n * H + col] + acc2[rg][cg][r] + bb;
                    h[(size_t)n * H + col] = hv;
                    const unsigned short hb = f2bf(hv);
                    h_bf[(size_t)n * H + col] = hb;
                    if (PROD) {
                        const int byteoff =
                            16384 + row * 256 + ((col * 2) ^ ((row & 7) << 4));
                        *reinterpret_cast<unsigned short*>(
                            reinterpret_cast<char*>(X) + byteoff) = hb;
                    }
                } else if (PROD) {
                    const int byteoff =
                        16384 + row * 256 + ((col * 2) ^ ((row & 7) << 4));
                    *reinterpret_cast<unsigned short*>(
                        reinterpret_cast<char*>(X) + byteoff) = 0;
                }
            }
        }
    }

    if (PROD) {
        bf16x8 B3[2][4], B4[2][4];
#pragma unroll
        for (int cg = 0; cg < 2; ++cg) {
            const int col = w * 32 + cg * 16 + l15;
#pragma unroll
            for (int s = 0; s < 4; ++s) {
                B3[cg][s] = *reinterpret_cast<const bf16x8*>(
                    eW1tN + (size_t)col * 256 + s * 32 + lq * 8);
                B4[cg][s] = *reinterpret_cast<const bf16x8*>(
                    eW1tN + (size_t)col * 256 + 128 + s * 32 + lq * 8);
            }
        }
        __syncthreads();

        f32x4 acc3[4][2], acc4[4][2];
#pragma unroll
        for (int rg = 0; rg < 4; ++rg)
#pragma unroll
            for (int cg = 0; cg < 2; ++cg) {
                acc3[rg][cg] = (f32x4)0.f;
                acc4[rg][cg] = (f32x4)0.f;
            }

#pragma unroll
        for (int s = 0; s < 4; ++s) {
            bf16x8 a[4];
#pragma unroll
            for (int rg = 0; rg < 4; ++rg) {
                const int row = rg * 16 + l15;
                const int byteoff =
                    16384 + row * 256 + ((s * 64 + lq * 16) ^ ((row & 7) << 4));
                a[rg] = *reinterpret_cast<const bf16x8*>(
                    reinterpret_cast<const char*>(X) + byteoff);
            }
#pragma unroll
            for (int rg = 0; rg < 4; ++rg)
#pragma unroll
                for (int cg = 0; cg < 2; ++cg) {
                    acc3[rg][cg] = __builtin_amdgcn_mfma_f32_16x16x32_bf16(
                        a[rg], B3[cg][s], acc3[rg][cg], 0, 0, 0);
                    acc4[rg][cg] = __builtin_amdgcn_mfma_f32_16x16x32_bf16(
                        a[rg], B4[cg][s], acc4[rg][cg], 0, 0, 0);
                }
        }

#pragma unroll
        for (int cg = 0; cg < 2; ++cg) {
            const int col = w * 32 + cg * 16 + l15;
            const float bb = eb1N[col];
#pragma unroll
            for (int rg = 0; rg < 4; ++rg) {
#pragma unroll
                for (int r = 0; r < 4; ++r) {
                    const int row = rg * 16 + lq * 4 + r;
                    const int n = n0 + row;
                    if (n < N) {
                        A_out[(size_t)n * H + col] = f2bf(acc3[rg][cg][r]);
                        B_out[(size_t)n * H + col] = acc4[rg][cg][r] + bb;
                    }
                }
            }
        }
    }
}

// ---------------- fp32 helper for encoder/decoder -------------------------
template <int K4>
__device__ __forceinline__ void mlp_layer(const float* __restrict__ W,
                                          const float* lds, int ldsStride,
                                          int c0, int egBase,
                                          float a0[8], float a1[8]) {
#pragma unroll 2
    for (int k4 = 0; k4 < K4; ++k4) {
        const float w00 = W[(k4 * 4 + 0) * H + c0];
        const float w01 = W[(k4 * 4 + 1) * H + c0];
        const float w02 = W[(k4 * 4 + 2) * H + c0];
        const float w03 = W[(k4 * 4 + 3) * H + c0];
        const float w10 = W[(k4 * 4 + 0) * H + c0 + 64];
        const float w11 = W[(k4 * 4 + 1) * H + c0 + 64];
        const float w12 = W[(k4 * 4 + 2) * H + c0 + 64];
        const float w13 = W[(k4 * 4 + 3) * H + c0 + 64];
#pragma unroll
        for (int e = 0; e < 8; ++e) {
            const float4 x = *reinterpret_cast<const float4*>(
                &lds[(egBase + e) * ldsStride + k4 * 4]);
            a0[e] = fmaf(x.x, w00, a0[e]);
            a0[e] = fmaf(x.y, w01, a0[e]);
            a0[e] = fmaf(x.z, w02, a0[e]);
            a0[e] = fmaf(x.w, w03, a0[e]);
            a1[e] = fmaf(x.x, w10, a1[e]);
            a1[e] = fmaf(x.y, w11, a1[e]);
            a1[e] = fmaf(x.z, w12, a1[e]);
            a1[e] = fmaf(x.w, w13, a1[e]);
        }
    }
}

// ---------------- encoder: [N,16] -> MLP -> h fp32 + h_bf bf16 ------------
__global__ __launch_bounds__(NTHR) void encode_kernel(
    const float* __restrict__ nf, const float* __restrict__ W1,
    const float* __restrict__ b1, const float* __restrict__ W2,
    const float* __restrict__ b2, float* __restrict__ h,
    unsigned short* __restrict__ h_bf, int N) {
    __shared__ float xin[TILE * 16];
    __shared__ float hm[TILE * H];
    const int t = threadIdx.x;
    const int n0 = blockIdx.x * TILE;
    const int c0 = t & 63;
    const int eg = t >> 6;

    for (int i = t; i < TILE * 16; i += NTHR) {
        const int gi = n0 * 16 + i;
        xin[i] = (gi < N * 16) ? nf[gi] : 0.f;
    }
    __syncthreads();

    float a0[8], a1[8];
#pragma unroll
    for (int e = 0; e < 8; ++e) { a0[e] = 0.f; a1[e] = 0.f; }
    mlp_layer<4>(W1, xin, 16, c0, eg * 8, a0, a1);
    {
        const float bb0 = b1[c0], bb1 = b1[c0 + 64];
#pragma unroll
        for (int e = 0; e < 8; ++e) {
            hm[(eg * 8 + e) * H + c0] = gelu_fast(a0[e] + bb0);
            hm[(eg * 8 + e) * H + c0 + 64] = gelu_fast(a1[e] + bb1);
        }
    }
    __syncthreads();
#pragma unroll
    for (int e = 0; e < 8; ++e) { a0[e] = 0.f; a1[e] = 0.f; }
    mlp_layer<32>(W2, hm, H, c0, eg * 8, a0, a1);
    const float bb0 = b2[c0], bb1 = b2[c0 + 64];
#pragma unroll
    for (int e = 0; e < 8; ++e) {
        const int n = n0 + eg * 8 + e;
        if (n < N) {
            const float v0 = a0[e] + bb0, v1 = a1[e] + bb1;
            h[(size_t)n * H + c0] = v0;
            h[(size_t)n * H + c0 + 64] = v1;
            h_bf[(size_t)n * H + c0] = f2bf(v0);
            h_bf[(size_t)n * H + c0 + 64] = f2bf(v1);
        }
    }
}

// --------------- decoder: h -> GELU MLP -> out [N,8] ----------------------
__global__ __launch_bounds__(NTHR) void decode_kernel(
    const float* __restrict__ h, const float* __restrict__ W1,
    const float* __restrict__ b1, const float* __restrict__ W2,
    const float* __restrict__ b2, float* __restrict__ out, int N) {
    __shared__ float xin[TILE * H];
    __shared__ float hm[TILE * 132];
    const int t = threadIdx.x;
    const int n0 = blockIdx.x * TILE;
    const int c0 = t & 63;
    const int eg = t >> 6;
    {
        const int col = t & 127;
        for (int e = t >> 7; e < TILE; e += 2) {
            const int n = n0 + e;
            xin[e * H + col] = (n < N) ? h[(size_t)n * H + col] : 0.f;
        }
    }
    __syncthreads();

    float a0[8], a1[8];
#pragma unroll
    for (int e = 0; e < 8; ++e) { a0[e] = 0.f; a1[e] = 0.f; }
    mlp_layer<32>(W1, xin, H, c0, eg * 8, a0, a1);
    {
        const float bb0 = b1[c0], bb1 = b1[c0 + 64];
#pragma unroll
        for (int e = 0; e < 8; ++e) {
            hm[(eg * 8 + e) * 132 + c0] = gelu_fast(a0[e] + bb0);
            hm[(eg * 8 + e) * 132 + c0 + 64] = gelu_fast(a1[e] + bb1);
        }
    }
    __syncthreads();
    {
        const int e = t >> 3;
        const int o = t & 7;
        const int n = n0 + e;
        float acc = b2[o];
#pragma unroll 4
        for (int k = 0; k < H; ++k)
            acc = fmaf(hm[e * 132 + k], W2[k * 8 + o], acc);
        if (n < N) out[n * 8 + o] = acc;
    }
}

extern "C" void kernel_launch(void* const* d_in, const int* in_sizes, int n_in,
                              void* d_out, int out_size, void* d_ws,
                              size_t ws_size, hipStream_t stream) {
    (void)n_in; (void)out_size; (void)ws_size;
    const float* nf      = (const float*)d_in[0];
    const int*   ei      = (const int*)d_in[1];
    const float* enc_W1  = (const float*)d_in[2];
    const float* enc_b1  = (const float*)d_in[3];
    const float* enc_W2  = (const float*)d_in[4];
    const float* enc_b2  = (const float*)d_in[5];
    const float* edge_W1 = (const float*)d_in[6];
    const float* edge_b1 = (const float*)d_in[7];
    const float* edge_W2 = (const float*)d_in[8];
    const float* edge_b2 = (const float*)d_in[9];
    const float* node_W1 = (const float*)d_in[10];
    const float* node_b1 = (const float*)d_in[11];
    const float* node_W2 = (const float*)d_in[12];
    const float* node_b2 = (const float*)d_in[13];
    const float* dec_W1  = (const float*)d_in[14];
    const float* dec_b1  = (const float*)d_in[15];
    const float* dec_W2  = (const float*)d_in[16];
    const float* dec_b2  = (const float*)d_in[17];

    const int N = in_sizes[0] / 16;
    const int E = in_sizes[1] / 2;
    const int L = in_sizes[7] / H;  // edge_b1 is [L,H]
    const int numChunks = (E >> 5) + 1;

    // ---------------- workspace layout ----------------
    char* ws = (char*)d_ws;
    float* h    = (float*)ws;                    ws += (size_t)N * H * 4;
    float* aggG = (float*)ws;                    ws += (size_t)N * H * 4;
    float* Bf32 = (float*)ws;                    ws += (size_t)N * H * 4;
    unsigned short* h_bf  = (unsigned short*)ws; ws += (size_t)N * H * 2;
    unsigned short* A_bf  = (unsigned short*)ws; ws += (size_t)N * H * 2;
    int* srcS     = (int*)ws;                    ws += (size_t)E * 4;
    int* deg      = (int*)ws;                    ws += (size_t)N * 4;
    int* rowStart = (int*)ws;                    ws += (size_t)(N + 1) * 4;
    int* cursor   = (int*)ws;                    ws += (size_t)N * 4;
    int* bsum     = (int*)ws;                    ws += (size_t)256 * 4;
    int* chunkLo  = (int*)ws;                    ws += (size_t)numChunks * 4;
    unsigned short* eW1t = (unsigned short*)ws;  ws += (size_t)L * 2 * H * H * 2;
    unsigned short* nW1tc = (unsigned short*)ws; ws += (size_t)L * 2 * H * H * 2;
    unsigned short* nW2t = (unsigned short*)ws;  ws += (size_t)L * H * H * 2;
    float* cvec   = (float*)ws;                  ws += (size_t)L * H * 4;

    const int* srcArr = ei;
    const int* dstArr = ei + E;

    // ---- weight prep (tiny) ----
    {
        const int t1 = L * 2 * H * H, t2 = L * H * H;
        wcvt_kernel<<<(t1 + NTHR - 1) / NTHR, NTHR, 0, stream>>>(edge_W1, eW1t, 2 * H, H, t1);
        wcvt_kernel<<<(t2 + NTHR - 1) / NTHR, NTHR, 0, stream>>>(node_W2, nW2t, H, H, t2);
        wcvt_top_kernel<<<(t2 + NTHR - 1) / NTHR, NTHR, 0, stream>>>(node_W1, nW1tc, t2);
        wcomb_kernel<<<dim3(H + 1, L), H, 0, stream>>>(edge_W2, edge_b2,
                                                       node_W1, nW1tc, cvec);
    }

    // ---- sort edges by dst (hist + multiblock scan + scatter) ----
    hipMemsetAsync(deg, 0, (size_t)N * 4, stream);
    deg_kernel<<<(E + NTHR - 1) / NTHR, NTHR, 0, stream>>>(dstArr, deg, E);
    const int nScanB = (N + 1023) / 1024;
    scan1_kernel<<<nScanB, 1024, 0, stream>>>(deg, rowStart, bsum, N);
    scan2_kernel<<<1, 64, 0, stream>>>(bsum, nScanB);
    scan3_kernel<<<(N + 1 + NTHR - 1) / NTHR, NTHR, 0, stream>>>(
        rowStart, cursor, bsum, N, E);
    hipMemsetAsync(chunkLo, 0x7f, (size_t)numChunks * 4, stream);
    chunk_kernel<<<(N + NTHR - 1) / NTHR, NTHR, 0, stream>>>(rowStart, chunkLo, N);
    scatter_kernel<<<(E + NTHR - 1) / NTHR, NTHR, 0, stream>>>(srcArr, dstArr,
                                                               cursor, srcS, E);

    const int encBlocks  = (N + TILE - 1) / TILE;
    const int tileBlocks = (N + TE - 1) / TE;
    const int gatherBlks = (numChunks + 3) / 4;

    encode_kernel<<<encBlocks, NTHR, 0, stream>>>(nf, enc_W1, enc_b1, enc_W2,
                                                  enc_b2, h, h_bf, N);
    ab_kernel<<<tileBlocks, NTHR, 0, stream>>>(h_bf, eW1t, edge_b1, A_bf, Bf32,
                                               N);
    for (int l = 0; l < L; ++l) {
        edge_gather_kernel<<<gatherBlks, NTHR, 0, stream>>>(
            A_bf, Bf32, srcS, rowStart, chunkLo, aggG, N, E);
        if (l + 1 < L) {
            node_fused_kernel<true><<<tileBlocks, NTHR, 0, stream>>>(
                h, h_bf, aggG, deg, nW1tc + (size_t)l * 2 * H * H,
                node_b1 + (size_t)l * H, cvec + (size_t)l * H,
                nW2t + (size_t)l * H * H, node_b2 + (size_t)l * H,
                eW1t + (size_t)(l + 1) * 2 * H * H,
                edge_b1 + (size_t)(l + 1) * H, A_bf, Bf32, N);
        } else {
            node_fused_kernel<false><<<tileBlocks, NTHR, 0, stream>>>(
                h, h_bf, aggG, deg, nW1tc + (size_t)l * 2 * H * H,
                node_b1 + (size_t)l * H, cvec + (size_t)l * H,
                nW2t + (size_t)l * H * H, node_b2 + (size_t)l * H, nullptr,
                nullptr, nullptr, nullptr, N);
        }
    }
    decode_kernel<<<encBlocks, NTHR, 0, stream>>>(h, dec_W1, dec_b1, dec_W2,
                                                  dec_b2, (float*)d_out, N);
}